// Round 1
// baseline (682.172 us; speedup 1.0000x reference)
//
#include <hip/hip_runtime.h>
#include <math.h>

#define NN 50000
#define FEAT 32
#define HID 256
#define NGRAPH 64
#define CAP 64

// ---------------- degree / normalization ----------------
__global__ void k_degree(const int* __restrict__ dst, int* __restrict__ cnt, int E) {
    int e = blockIdx.x * blockDim.x + threadIdx.x;
    if (e < E) atomicAdd(&cnt[dst[e]], 1);
}

__global__ void k_gcount(const int* __restrict__ batch, int* __restrict__ counts, int N) {
    int i = blockIdx.x * blockDim.x + threadIdx.x;
    if (i < N) atomicAdd(&counts[batch[i]], 1);
}

__global__ void k_dis(const int* __restrict__ cnt, float* __restrict__ dis, int N) {
    int i = blockIdx.x * blockDim.x + threadIdx.x;
    if (i < N) dis[i] = 1.0f / sqrtf((float)(cnt[i] + 1));   // +1 = self-loop
}

// ---------------- CSR-by-dst build (fixed-capacity buckets) ----------------
__global__ void k_scatter(const int* __restrict__ src, const int* __restrict__ dst,
                          int* __restrict__ counter, int* __restrict__ csr, int E) {
    int e = blockIdx.x * blockDim.x + threadIdx.x;
    if (e < E) {
        int d = dst[e];
        int p = atomicAdd(&counter[d], 1);
        if (p < CAP) csr[d * CAP + p] = src[e];
    }
}

// ---------------- fp32 GEMM: C[M,256] = A[M,K] @ W[K,256] ----------------
// block 256 threads: 32 rows/block, each thread 4 rows x 8 cols
__global__ void k_mm(const float* __restrict__ A, const float* __restrict__ W,
                     float* __restrict__ C, int M, int K) {
    int t = threadIdx.x;
    int tcol = t & 31;            // 0..31
    int trow = t >> 5;            // 0..7
    int row0 = blockIdx.x * 32 + trow * 4;
    int col0 = tcol * 8;
    float acc[4][8];
#pragma unroll
    for (int r = 0; r < 4; ++r)
#pragma unroll
        for (int c = 0; c < 8; ++c) acc[r][c] = 0.f;

    bool full = (row0 + 3) < M;
    for (int k = 0; k < K; ++k) {
        const float4 w0 = *(const float4*)&W[k * HID + col0];
        const float4 w1 = *(const float4*)&W[k * HID + col0 + 4];
        float a[4];
        if (full) {
#pragma unroll
            for (int r = 0; r < 4; ++r) a[r] = A[(size_t)(row0 + r) * K + k];
        } else {
#pragma unroll
            for (int r = 0; r < 4; ++r) a[r] = (row0 + r < M) ? A[(size_t)(row0 + r) * K + k] : 0.f;
        }
#pragma unroll
        for (int r = 0; r < 4; ++r) {
            acc[r][0] += a[r] * w0.x; acc[r][1] += a[r] * w0.y;
            acc[r][2] += a[r] * w0.z; acc[r][3] += a[r] * w0.w;
            acc[r][4] += a[r] * w1.x; acc[r][5] += a[r] * w1.y;
            acc[r][6] += a[r] * w1.z; acc[r][7] += a[r] * w1.w;
        }
    }
#pragma unroll
    for (int r = 0; r < 4; ++r) {
        int row = row0 + r;
        if (row < M) {
            *(float4*)&C[(size_t)row * HID + col0]     = make_float4(acc[r][0], acc[r][1], acc[r][2], acc[r][3]);
            *(float4*)&C[(size_t)row * HID + col0 + 4] = make_float4(acc[r][4], acc[r][5], acc[r][6], acc[r][7]);
        }
    }
}

// ---------------- aggregation: one wave per dst node ----------------
// out[d] = relu( sum_{e: dst=d} h[src]*dis[src]*dis[d] + h[d]*dis[d]^2 + bias )
__global__ void k_agg(const float* __restrict__ h, const int* __restrict__ cnt,
                      const int* __restrict__ csr, const float* __restrict__ dis,
                      const float* __restrict__ bias, float* __restrict__ out, int N) {
    int wid = (int)((blockIdx.x * (size_t)blockDim.x + threadIdx.x) >> 6);
    if (wid >= N) return;
    int lane = threadIdx.x & 63;
    int c0 = lane * 4;

    float dn = dis[wid];
    float4 hv = *(const float4*)&h[(size_t)wid * HID + c0];
    float sw = dn * dn;                                     // self-loop norm 1/deg
    float4 acc = make_float4(hv.x * sw, hv.y * sw, hv.z * sw, hv.w * sw);

    int e = cnt[wid]; if (e > CAP) e = CAP;
    const int* lst = &csr[(size_t)wid * CAP];
    for (int i = 0; i < e; ++i) {
        int s = lst[i];
        float w = dis[s] * dn;
        float4 v = *(const float4*)&h[(size_t)s * HID + c0];
        acc.x += w * v.x; acc.y += w * v.y; acc.z += w * v.z; acc.w += w * v.w;
    }
    float4 b = *(const float4*)&bias[c0];
    acc.x = fmaxf(acc.x + b.x, 0.f);
    acc.y = fmaxf(acc.y + b.y, 0.f);
    acc.z = fmaxf(acc.z + b.z, 0.f);
    acc.w = fmaxf(acc.w + b.w, 0.f);
    *(float4*)&out[(size_t)wid * HID + c0] = acc;
}

// ---------------- segmented mean-pool (batch is sorted) ----------------
// block handles 128 nodes, thread c = one of 256 cols; flush on graph change
__global__ void k_pool(const float* __restrict__ z, const int* __restrict__ batch,
                       float* __restrict__ pooled, int N) {
    int c = threadIdx.x;                 // 0..255
    int base = blockIdx.x * 128;
    if (base >= N) return;
    int end = base + 128; if (end > N) end = N;
    int cur = batch[base];
    float acc = 0.f;
    for (int n = base; n < end; ++n) {
        int g = batch[n];
        if (g != cur) {
            atomicAdd(&pooled[(size_t)cur * HID + c], acc);
            acc = 0.f; cur = g;
        }
        acc += z[(size_t)n * HID + c];
    }
    atomicAdd(&pooled[(size_t)cur * HID + c], acc);
}

// ---------------- head: mls = (sums/cnt) @ Wf + bf ; split -> mean, std ----------------
__global__ void k_head(const float* __restrict__ pooled, const int* __restrict__ counts,
                       const float* __restrict__ Wf, const float* __restrict__ bf,
                       float* __restrict__ out) {
    int t = blockIdx.x * blockDim.x + threadIdx.x;
    if (t >= NGRAPH * 12) return;
    int g = t / 12, j = t % 12;
    float inv = 1.f / fmaxf((float)counts[g], 1.f);
    float s = 0.f;
    for (int k = 0; k < HID; ++k) s += pooled[(size_t)g * HID + k] * Wf[k * 12 + j];
    s = s * inv + bf[j];
    if (j < 6) {
        out[g * 6 + j] = s;
    } else {
        float ls = fminf(fmaxf(s, -20.f), 2.f);
        out[NGRAPH * 6 + g * 6 + (j - 6)] = expf(ls);
    }
}

// ---------------- launch ----------------
extern "C" void kernel_launch(void* const* d_in, const int* in_sizes, int n_in,
                              void* d_out, int out_size, void* d_ws, size_t ws_size,
                              hipStream_t stream) {
    const float* x     = (const float*)d_in[0];
    const int*   ei    = (const int*)d_in[1];
    const int*   batch = (const int*)d_in[2];
    const float* W1    = (const float*)d_in[3];
    const float* b1    = (const float*)d_in[4];
    const float* W2    = (const float*)d_in[5];
    const float* b2    = (const float*)d_in[6];
    const float* Wf    = (const float*)d_in[7];
    const float* bfv   = (const float*)d_in[8];
    float* out = (float*)d_out;

    const int E = in_sizes[1] / 2;
    const int N = in_sizes[2];
    const int* srcp = ei;
    const int* dstp = ei + E;

    // workspace layout (256B aligned segments)
    char* ws = (char*)d_ws;
    const size_t OFF_CNT    = 0;                          // int[NN]      200000 -> 200192
    const size_t OFF_CTR    = 200192;                     // int[NN]      -> 400384
    const size_t OFF_COUNTS = 400384;                     // int[64]      -> 400640
    const size_t OFF_POOLED = 400640;                     // f32[64*256]  -> 466176
    const size_t ZERO_BYTES = 466176;
    const size_t OFF_DIS    = 466176;                     // f32[NN]      -> 666368
    const size_t OFF_CSR    = 666368;                     // int[NN*CAP]  -> 13466368
    const size_t OFF_A      = 13466368;                   // f32[NN*256]  -> 64666368
    const size_t OFF_B      = 64666368;                   // f32[NN*256]  -> 115866368

    int*   cnt    = (int*)(ws + OFF_CNT);
    int*   ctr    = (int*)(ws + OFF_CTR);
    int*   counts = (int*)(ws + OFF_COUNTS);
    float* pooled = (float*)(ws + OFF_POOLED);
    float* dis    = (float*)(ws + OFF_DIS);
    int*   csr    = (int*)(ws + OFF_CSR);
    float* bufA   = (float*)(ws + OFF_A);
    float* bufB   = (float*)(ws + OFF_B);

    hipMemsetAsync(ws, 0, ZERO_BYTES, stream);

    const int T = 256;
    k_degree<<<(E + T - 1) / T, T, 0, stream>>>(dstp, cnt, E);
    k_gcount<<<(N + T - 1) / T, T, 0, stream>>>(batch, counts, N);
    k_dis<<<(N + T - 1) / T, T, 0, stream>>>(cnt, dis, N);
    k_scatter<<<(E + T - 1) / T, T, 0, stream>>>(srcp, dstp, ctr, csr, E);

    // layer 1: h1 = x @ W1 ; aggregate (+b1, relu)
    k_mm<<<(N + 31) / 32, T, 0, stream>>>(x, W1, bufA, N, FEAT);
    k_agg<<<(N * 64 + T - 1) / T, T, 0, stream>>>(bufA, cnt, csr, dis, b1, bufB, N);

    // layer 2: h2 = z1 @ W2 ; aggregate (+b2, relu)
    k_mm<<<(N + 31) / 32, T, 0, stream>>>(bufB, W2, bufA, N, HID);
    k_agg<<<(N * 64 + T - 1) / T, T, 0, stream>>>(bufA, cnt, csr, dis, b2, bufB, N);

    // pool + head
    k_pool<<<(N + 127) / 128, T, 0, stream>>>(bufB, batch, pooled, N);
    k_head<<<3, T, 0, stream>>>(pooled, counts, Wf, bfv, out);
}

// Round 2
// 446.516 us; speedup vs baseline: 1.5278x; 1.5278x over previous
//
#include <hip/hip_runtime.h>
#include <math.h>

#define NN 50000
#define FEAT 32
#define HID 256
#define NGRAPH 64
#define CAP 64

// ---------------- degree / normalization ----------------
__global__ void k_degree(const int* __restrict__ dst, int* __restrict__ cnt, int E) {
    int e = blockIdx.x * blockDim.x + threadIdx.x;
    if (e < E) atomicAdd(&cnt[dst[e]], 1);
}

// batch is sorted: record the start index of every graph segment.
// starts[] has NGRAPH+1 entries; starts[NGRAPH] = N.
__global__ void k_gbounds(const int* __restrict__ batch, int* __restrict__ starts, int N) {
    int i = blockIdx.x * blockDim.x + threadIdx.x;
    if (i >= N) return;
    int b = batch[i];
    int prev = (i == 0) ? -1 : batch[i - 1];
    if (b != prev) {
        for (int g = prev + 1; g <= b; ++g) starts[g] = i;   // empty graphs collapse
    }
    if (i == N - 1) {
        for (int g = b + 1; g <= NGRAPH; ++g) starts[g] = N;
    }
}

__global__ void k_dis(const int* __restrict__ cnt, float* __restrict__ dis, int N) {
    int i = blockIdx.x * blockDim.x + threadIdx.x;
    if (i < N) dis[i] = 1.0f / sqrtf((float)(cnt[i] + 1));   // +1 = self-loop
}

// ---------------- CSR-by-dst build (fixed-capacity buckets) ----------------
__global__ void k_scatter(const int* __restrict__ src, const int* __restrict__ dst,
                          int* __restrict__ counter, int* __restrict__ csr, int E) {
    int e = blockIdx.x * blockDim.x + threadIdx.x;
    if (e < E) {
        int d = dst[e];
        int p = atomicAdd(&counter[d], 1);
        if (p < CAP) csr[d * CAP + p] = src[e];
    }
}

// ---------------- fp32 GEMM: C[M,256] = A[M,K] @ W[K,256] ----------------
// block 256 threads: 32 rows/block, each thread 4 rows x 8 cols
__global__ void k_mm(const float* __restrict__ A, const float* __restrict__ W,
                     float* __restrict__ C, int M, int K) {
    int t = threadIdx.x;
    int tcol = t & 31;            // 0..31
    int trow = t >> 5;            // 0..7
    int row0 = blockIdx.x * 32 + trow * 4;
    int col0 = tcol * 8;
    float acc[4][8];
#pragma unroll
    for (int r = 0; r < 4; ++r)
#pragma unroll
        for (int c = 0; c < 8; ++c) acc[r][c] = 0.f;

    bool full = (row0 + 3) < M;
    for (int k = 0; k < K; ++k) {
        const float4 w0 = *(const float4*)&W[k * HID + col0];
        const float4 w1 = *(const float4*)&W[k * HID + col0 + 4];
        float a[4];
        if (full) {
#pragma unroll
            for (int r = 0; r < 4; ++r) a[r] = A[(size_t)(row0 + r) * K + k];
        } else {
#pragma unroll
            for (int r = 0; r < 4; ++r) a[r] = (row0 + r < M) ? A[(size_t)(row0 + r) * K + k] : 0.f;
        }
#pragma unroll
        for (int r = 0; r < 4; ++r) {
            acc[r][0] += a[r] * w0.x; acc[r][1] += a[r] * w0.y;
            acc[r][2] += a[r] * w0.z; acc[r][3] += a[r] * w0.w;
            acc[r][4] += a[r] * w1.x; acc[r][5] += a[r] * w1.y;
            acc[r][6] += a[r] * w1.z; acc[r][7] += a[r] * w1.w;
        }
    }
#pragma unroll
    for (int r = 0; r < 4; ++r) {
        int row = row0 + r;
        if (row < M) {
            *(float4*)&C[(size_t)row * HID + col0]     = make_float4(acc[r][0], acc[r][1], acc[r][2], acc[r][3]);
            *(float4*)&C[(size_t)row * HID + col0 + 4] = make_float4(acc[r][4], acc[r][5], acc[r][6], acc[r][7]);
        }
    }
}

// ---------------- aggregation: one wave per dst node ----------------
// out[d] = relu( sum_{e: dst=d} h[src]*dis[src]*dis[d] + h[d]*dis[d]^2 + bias )
__global__ void k_agg(const float* __restrict__ h, const int* __restrict__ cnt,
                      const int* __restrict__ csr, const float* __restrict__ dis,
                      const float* __restrict__ bias, float* __restrict__ out, int N) {
    int wid = (int)((blockIdx.x * (size_t)blockDim.x + threadIdx.x) >> 6);
    if (wid >= N) return;
    int lane = threadIdx.x & 63;
    int c0 = lane * 4;

    float dn = dis[wid];
    float4 hv = *(const float4*)&h[(size_t)wid * HID + c0];
    float sw = dn * dn;                                     // self-loop norm 1/deg
    float4 acc = make_float4(hv.x * sw, hv.y * sw, hv.z * sw, hv.w * sw);

    int e = cnt[wid]; if (e > CAP) e = CAP;
    const int* lst = &csr[(size_t)wid * CAP];
    for (int i = 0; i < e; ++i) {
        int s = lst[i];
        float w = dis[s] * dn;
        float4 v = *(const float4*)&h[(size_t)s * HID + c0];
        acc.x += w * v.x; acc.y += w * v.y; acc.z += w * v.z; acc.w += w * v.w;
    }
    float4 b = *(const float4*)&bias[c0];
    acc.x = fmaxf(acc.x + b.x, 0.f);
    acc.y = fmaxf(acc.y + b.y, 0.f);
    acc.z = fmaxf(acc.z + b.z, 0.f);
    acc.w = fmaxf(acc.w + b.w, 0.f);
    *(float4*)&out[(size_t)wid * HID + c0] = acc;
}

// ---------------- segmented mean-pool (batch is sorted) ----------------
// block handles 128 nodes, thread c = one of 256 cols; flush on graph change
__global__ void k_pool(const float* __restrict__ z, const int* __restrict__ batch,
                       float* __restrict__ pooled, int N) {
    int c = threadIdx.x;                 // 0..255
    int base = blockIdx.x * 128;
    if (base >= N) return;
    int end = base + 128; if (end > N) end = N;
    int cur = batch[base];
    float acc = 0.f;
    for (int n = base; n < end; ++n) {
        int g = batch[n];
        if (g != cur) {
            atomicAdd(&pooled[(size_t)cur * HID + c], acc);
            acc = 0.f; cur = g;
        }
        acc += z[(size_t)n * HID + c];
    }
    atomicAdd(&pooled[(size_t)cur * HID + c], acc);
}

// ---------------- head: mls = (sums/cnt) @ Wf + bf ; split -> mean, std ----------------
__global__ void k_head(const float* __restrict__ pooled, const int* __restrict__ starts,
                       const float* __restrict__ Wf, const float* __restrict__ bf,
                       float* __restrict__ out) {
    int t = blockIdx.x * blockDim.x + threadIdx.x;
    if (t >= NGRAPH * 12) return;
    int g = t / 12, j = t % 12;
    float cntf = (float)(starts[g + 1] - starts[g]);
    float inv = 1.f / fmaxf(cntf, 1.f);
    float s = 0.f;
    for (int k = 0; k < HID; ++k) s += pooled[(size_t)g * HID + k] * Wf[k * 12 + j];
    s = s * inv + bf[j];
    if (j < 6) {
        out[g * 6 + j] = s;
    } else {
        float ls = fminf(fmaxf(s, -20.f), 2.f);
        out[NGRAPH * 6 + g * 6 + (j - 6)] = expf(ls);
    }
}

// ---------------- launch ----------------
extern "C" void kernel_launch(void* const* d_in, const int* in_sizes, int n_in,
                              void* d_out, int out_size, void* d_ws, size_t ws_size,
                              hipStream_t stream) {
    const float* x     = (const float*)d_in[0];
    const int*   ei    = (const int*)d_in[1];
    const int*   batch = (const int*)d_in[2];
    const float* W1    = (const float*)d_in[3];
    const float* b1    = (const float*)d_in[4];
    const float* W2    = (const float*)d_in[5];
    const float* b2    = (const float*)d_in[6];
    const float* Wf    = (const float*)d_in[7];
    const float* bfv   = (const float*)d_in[8];
    float* out = (float*)d_out;

    const int E = in_sizes[1] / 2;
    const int N = in_sizes[2];
    const int* srcp = ei;
    const int* dstp = ei + E;

    // workspace layout (256B aligned segments)
    char* ws = (char*)d_ws;
    const size_t OFF_CNT    = 0;                          // int[NN]      200000 -> 200192
    const size_t OFF_CTR    = 200192;                     // int[NN]      -> 400384
    const size_t OFF_STARTS = 400384;                     // int[65]      -> 400640
    const size_t OFF_POOLED = 400640;                     // f32[64*256]  -> 466176
    const size_t ZERO_BYTES = 466176;
    const size_t OFF_DIS    = 466176;                     // f32[NN]      -> 666368
    const size_t OFF_CSR    = 666368;                     // int[NN*CAP]  -> 13466368
    const size_t OFF_A      = 13466368;                   // f32[NN*256]  -> 64666368
    const size_t OFF_B      = 64666368;                   // f32[NN*256]  -> 115866368

    int*   cnt    = (int*)(ws + OFF_CNT);
    int*   ctr    = (int*)(ws + OFF_CTR);
    int*   starts = (int*)(ws + OFF_STARTS);
    float* pooled = (float*)(ws + OFF_POOLED);
    float* dis    = (float*)(ws + OFF_DIS);
    int*   csr    = (int*)(ws + OFF_CSR);
    float* bufA   = (float*)(ws + OFF_A);
    float* bufB   = (float*)(ws + OFF_B);

    hipMemsetAsync(ws, 0, ZERO_BYTES, stream);

    const int T = 256;
    k_degree<<<(E + T - 1) / T, T, 0, stream>>>(dstp, cnt, E);
    k_gbounds<<<(N + T - 1) / T, T, 0, stream>>>(batch, starts, N);
    k_dis<<<(N + T - 1) / T, T, 0, stream>>>(cnt, dis, N);
    k_scatter<<<(E + T - 1) / T, T, 0, stream>>>(srcp, dstp, ctr, csr, E);

    // layer 1: h1 = x @ W1 ; aggregate (+b1, relu)
    k_mm<<<(N + 31) / 32, T, 0, stream>>>(x, W1, bufA, N, FEAT);
    k_agg<<<(N * 64 + T - 1) / T, T, 0, stream>>>(bufA, cnt, csr, dis, b1, bufB, N);

    // layer 2: h2 = z1 @ W2 ; aggregate (+b2, relu)
    k_mm<<<(N + 31) / 32, T, 0, stream>>>(bufB, W2, bufA, N, HID);
    k_agg<<<(N * 64 + T - 1) / T, T, 0, stream>>>(bufA, cnt, csr, dis, b2, bufB, N);

    // pool + head
    k_pool<<<(N + 127) / 128, T, 0, stream>>>(bufB, batch, pooled, N);
    k_head<<<3, T, 0, stream>>>(pooled, starts, Wf, bfv, out);
}

// Round 3
// 440.296 us; speedup vs baseline: 1.5493x; 1.0141x over previous
//
#include <hip/hip_runtime.h>
#include <math.h>

#define NN 50000
#define FEAT 32
#define HID 256
#define NGRAPH 64
#define CAP 64

// ---------------- degree / normalization ----------------
__global__ void k_degree(const int* __restrict__ dst, int* __restrict__ cnt, int E) {
    int e = blockIdx.x * blockDim.x + threadIdx.x;
    if (e < E) atomicAdd(&cnt[dst[e]], 1);
}

// batch is sorted: record the start index of every graph segment.
// starts[] has NGRAPH+1 entries; starts[NGRAPH] = N.
__global__ void k_gbounds(const int* __restrict__ batch, int* __restrict__ starts, int N) {
    int i = blockIdx.x * blockDim.x + threadIdx.x;
    if (i >= N) return;
    int b = batch[i];
    int prev = (i == 0) ? -1 : batch[i - 1];
    if (b != prev) {
        for (int g = prev + 1; g <= b; ++g) starts[g] = i;   // empty graphs collapse
    }
    if (i == N - 1) {
        for (int g = b + 1; g <= NGRAPH; ++g) starts[g] = N;
    }
}

__global__ void k_dis(const int* __restrict__ cnt, float* __restrict__ dis, int N) {
    int i = blockIdx.x * blockDim.x + threadIdx.x;
    if (i < N) dis[i] = 1.0f / sqrtf((float)(cnt[i] + 1));   // +1 = self-loop
}

// ---------------- CSR-by-dst build (fixed-capacity buckets) ----------------
__global__ void k_scatter(const int* __restrict__ src, const int* __restrict__ dst,
                          int* __restrict__ counter, int* __restrict__ csr, int E) {
    int e = blockIdx.x * blockDim.x + threadIdx.x;
    if (e < E) {
        int d = dst[e];
        int p = atomicAdd(&counter[d], 1);
        if (p < CAP) csr[d * CAP + p] = src[e];
    }
}

// ---------------- fp32 GEMM: C[M,256] = A[M,K] @ W[K,256] ----------------
// block 256 threads: 32 rows/block, thread = 4 rows x 8 cols.
// K-loop stepped by 4 with float4 A and W loads: 128 FMA per 12 loads.
__global__ void k_mm(const float* __restrict__ A, const float* __restrict__ W,
                     float* __restrict__ C, int M, int K) {
    int t = threadIdx.x;
    int tcol = t & 31;            // 0..31
    int trow = t >> 5;            // 0..7
    int row0 = blockIdx.x * 32 + trow * 4;
    int col0 = tcol * 8;
    float acc[4][8];
#pragma unroll
    for (int r = 0; r < 4; ++r)
#pragma unroll
        for (int c = 0; c < 8; ++c) acc[r][c] = 0.f;

    bool full = (row0 + 3) < M;
    if (full) {
        for (int k = 0; k < K; k += 4) {
            float4 av[4];
#pragma unroll
            for (int r = 0; r < 4; ++r)
                av[r] = *(const float4*)&A[(size_t)(row0 + r) * K + k];
            float4 wv[4][2];
#pragma unroll
            for (int i = 0; i < 4; ++i) {
                wv[i][0] = *(const float4*)&W[(size_t)(k + i) * HID + col0];
                wv[i][1] = *(const float4*)&W[(size_t)(k + i) * HID + col0 + 4];
            }
#pragma unroll
            for (int r = 0; r < 4; ++r) {
                const float* ap = (const float*)&av[r];
#pragma unroll
                for (int i = 0; i < 4; ++i) {
                    float a = ap[i];
                    const float* w0 = (const float*)&wv[i][0];
                    const float* w1 = (const float*)&wv[i][1];
                    acc[r][0] += a * w0[0]; acc[r][1] += a * w0[1];
                    acc[r][2] += a * w0[2]; acc[r][3] += a * w0[3];
                    acc[r][4] += a * w1[0]; acc[r][5] += a * w1[1];
                    acc[r][6] += a * w1[2]; acc[r][7] += a * w1[3];
                }
            }
        }
    } else {
        // tail block (at most 1 of ~1563): scalar-guarded path
        for (int k = 0; k < K; ++k) {
            const float4 w0 = *(const float4*)&W[(size_t)k * HID + col0];
            const float4 w1 = *(const float4*)&W[(size_t)k * HID + col0 + 4];
#pragma unroll
            for (int r = 0; r < 4; ++r) {
                float a = (row0 + r < M) ? A[(size_t)(row0 + r) * K + k] : 0.f;
                acc[r][0] += a * w0.x; acc[r][1] += a * w0.y;
                acc[r][2] += a * w0.z; acc[r][3] += a * w0.w;
                acc[r][4] += a * w1.x; acc[r][5] += a * w1.y;
                acc[r][6] += a * w1.z; acc[r][7] += a * w1.w;
            }
        }
    }
#pragma unroll
    for (int r = 0; r < 4; ++r) {
        int row = row0 + r;
        if (row < M) {
            *(float4*)&C[(size_t)row * HID + col0]     = make_float4(acc[r][0], acc[r][1], acc[r][2], acc[r][3]);
            *(float4*)&C[(size_t)row * HID + col0 + 4] = make_float4(acc[r][4], acc[r][5], acc[r][6], acc[r][7]);
        }
    }
}

// ---------------- aggregation: one wave per dst node ----------------
// out[d] = relu( sum_{e: dst=d} h[src]*dis[src]*dis[d] + h[d]*dis[d]^2 + bias )
__global__ void k_agg(const float* __restrict__ h, const int* __restrict__ cnt,
                      const int* __restrict__ csr, const float* __restrict__ dis,
                      const float* __restrict__ bias, float* __restrict__ out, int N) {
    int wid = (int)((blockIdx.x * (size_t)blockDim.x + threadIdx.x) >> 6);
    if (wid >= N) return;
    int lane = threadIdx.x & 63;
    int c0 = lane * 4;

    float dn = dis[wid];
    float4 hv = *(const float4*)&h[(size_t)wid * HID + c0];
    float sw = dn * dn;                                     // self-loop norm 1/deg
    float4 acc = make_float4(hv.x * sw, hv.y * sw, hv.z * sw, hv.w * sw);

    int e = cnt[wid]; if (e > CAP) e = CAP;
    const int* lst = &csr[(size_t)wid * CAP];
    for (int i = 0; i < e; ++i) {
        int s = lst[i];
        float w = dis[s] * dn;
        float4 v = *(const float4*)&h[(size_t)s * HID + c0];
        acc.x += w * v.x; acc.y += w * v.y; acc.z += w * v.z; acc.w += w * v.w;
    }
    float4 b = *(const float4*)&bias[c0];
    acc.x = fmaxf(acc.x + b.x, 0.f);
    acc.y = fmaxf(acc.y + b.y, 0.f);
    acc.z = fmaxf(acc.z + b.z, 0.f);
    acc.w = fmaxf(acc.w + b.w, 0.f);
    *(float4*)&out[(size_t)wid * HID + c0] = acc;
}

// ---------------- segmented mean-pool (batch is sorted) ----------------
__global__ void k_pool(const float* __restrict__ z, const int* __restrict__ batch,
                       float* __restrict__ pooled, int N) {
    int c = threadIdx.x;                 // 0..255
    int base = blockIdx.x * 128;
    if (base >= N) return;
    int end = base + 128; if (end > N) end = N;
    int cur = batch[base];
    float acc = 0.f;
    for (int n = base; n < end; ++n) {
        int g = batch[n];
        if (g != cur) {
            atomicAdd(&pooled[(size_t)cur * HID + c], acc);
            acc = 0.f; cur = g;
        }
        acc += z[(size_t)n * HID + c];
    }
    atomicAdd(&pooled[(size_t)cur * HID + c], acc);
}

// ---------------- head ----------------
__global__ void k_head(const float* __restrict__ pooled, const int* __restrict__ starts,
                       const float* __restrict__ Wf, const float* __restrict__ bf,
                       float* __restrict__ out) {
    int t = blockIdx.x * blockDim.x + threadIdx.x;
    if (t >= NGRAPH * 12) return;
    int g = t / 12, j = t % 12;
    float cntf = (float)(starts[g + 1] - starts[g]);
    float inv = 1.f / fmaxf(cntf, 1.f);
    float s = 0.f;
    for (int k = 0; k < HID; ++k) s += pooled[(size_t)g * HID + k] * Wf[k * 12 + j];
    s = s * inv + bf[j];
    if (j < 6) {
        out[g * 6 + j] = s;
    } else {
        float ls = fminf(fmaxf(s, -20.f), 2.f);
        out[NGRAPH * 6 + g * 6 + (j - 6)] = expf(ls);
    }
}

// ---------------- launch ----------------
extern "C" void kernel_launch(void* const* d_in, const int* in_sizes, int n_in,
                              void* d_out, int out_size, void* d_ws, size_t ws_size,
                              hipStream_t stream) {
    const float* x     = (const float*)d_in[0];
    const int*   ei    = (const int*)d_in[1];
    const int*   batch = (const int*)d_in[2];
    const float* W1    = (const float*)d_in[3];
    const float* b1    = (const float*)d_in[4];
    const float* W2    = (const float*)d_in[5];
    const float* b2    = (const float*)d_in[6];
    const float* Wf    = (const float*)d_in[7];
    const float* bfv   = (const float*)d_in[8];
    float* out = (float*)d_out;

    const int E = in_sizes[1] / 2;
    const int N = in_sizes[2];
    const int* srcp = ei;
    const int* dstp = ei + E;

    // workspace layout (256B aligned segments)
    char* ws = (char*)d_ws;
    const size_t OFF_CNT    = 0;                          // int[NN]      200000 -> 200192
    const size_t OFF_CTR    = 200192;                     // int[NN]      -> 400384
    const size_t OFF_STARTS = 400384;                     // int[65]      -> 400640
    const size_t OFF_POOLED = 400640;                     // f32[64*256]  -> 466176
    const size_t ZERO_BYTES = 466176;
    const size_t OFF_DIS    = 466176;                     // f32[NN]      -> 666368
    const size_t OFF_CSR    = 666368;                     // int[NN*CAP]  -> 13466368
    const size_t OFF_A      = 13466368;                   // f32[NN*256]  -> 64666368
    const size_t OFF_B      = 64666368;                   // f32[NN*256]  -> 115866368

    int*   cnt    = (int*)(ws + OFF_CNT);
    int*   ctr    = (int*)(ws + OFF_CTR);
    int*   starts = (int*)(ws + OFF_STARTS);
    float* pooled = (float*)(ws + OFF_POOLED);
    float* dis    = (float*)(ws + OFF_DIS);
    int*   csr    = (int*)(ws + OFF_CSR);
    float* bufA   = (float*)(ws + OFF_A);
    float* bufB   = (float*)(ws + OFF_B);

    hipMemsetAsync(ws, 0, ZERO_BYTES, stream);

    const int T = 256;
    k_degree<<<(E + T - 1) / T, T, 0, stream>>>(dstp, cnt, E);
    k_gbounds<<<(N + T - 1) / T, T, 0, stream>>>(batch, starts, N);
    k_dis<<<(N + T - 1) / T, T, 0, stream>>>(cnt, dis, N);
    k_scatter<<<(E + T - 1) / T, T, 0, stream>>>(srcp, dstp, ctr, csr, E);

    // layer 1: h1 = x @ W1 ; aggregate (+b1, relu)
    k_mm<<<(N + 31) / 32, T, 0, stream>>>(x, W1, bufA, N, FEAT);
    k_agg<<<(N * 64 + T - 1) / T, T, 0, stream>>>(bufA, cnt, csr, dis, b1, bufB, N);

    // layer 2: h2 = z1 @ W2 ; aggregate (+b2, relu)
    k_mm<<<(N + 31) / 32, T, 0, stream>>>(bufB, W2, bufA, N, HID);
    k_agg<<<(N * 64 + T - 1) / T, T, 0, stream>>>(bufA, cnt, csr, dis, b2, bufB, N);

    // pool + head
    k_pool<<<(N + 127) / 128, T, 0, stream>>>(bufB, batch, pooled, N);
    k_head<<<3, T, 0, stream>>>(pooled, starts, Wf, bfv, out);
}

// Round 4
// 242.118 us; speedup vs baseline: 2.8175x; 1.8185x over previous
//
#include <hip/hip_runtime.h>
#include <math.h>

#define NN 50000
#define FEAT 32
#define HID 256
#define NGRAPH 64
#define CAP 64

typedef __attribute__((ext_vector_type(8))) short bfrag;   // 8 bf16 (4 VGPRs)
typedef __attribute__((ext_vector_type(4))) float f32x4;   // MFMA accumulator

__device__ __forceinline__ float bf2f(unsigned short u) {
    union { unsigned int i; float f; } v; v.i = ((unsigned int)u) << 16; return v.f;
}
__device__ __forceinline__ unsigned short f2bf(float f) {
    union { float f; unsigned int i; } v; v.f = f;
    unsigned int r = v.i + 0x7fffu + ((v.i >> 16) & 1u);
    return (unsigned short)(r >> 16);
}

// ---------------- graph segment bounds (batch sorted) ----------------
__global__ void k_gbounds(const int* __restrict__ batch, int* __restrict__ starts, int N) {
    int i = blockIdx.x * blockDim.x + threadIdx.x;
    if (i >= N) return;
    int b = batch[i];
    int prev = (i == 0) ? -1 : batch[i - 1];
    if (b != prev) {
        for (int g = prev + 1; g <= b; ++g) starts[g] = i;
    }
    if (i == N - 1) {
        for (int g = b + 1; g <= NGRAPH; ++g) starts[g] = N;
    }
}

// ---------------- CSR-by-dst build; ctr ends up as in-degree ----------------
__global__ void k_scatter(const int* __restrict__ src, const int* __restrict__ dst,
                          int* __restrict__ counter, int* __restrict__ csr, int E) {
    int e = blockIdx.x * blockDim.x + threadIdx.x;
    if (e < E) {
        int d = dst[e];
        int p = atomicAdd(&counter[d], 1);
        if (p < CAP) csr[d * CAP + p] = src[e];
    }
}

__global__ void k_dis(const int* __restrict__ cnt, float* __restrict__ dis, int N) {
    int i = blockIdx.x * blockDim.x + threadIdx.x;
    if (i < N) dis[i] = 1.0f / sqrtf((float)(cnt[i] + 1));   // +1 = self-loop
}

// ---------------- W [K,256] -> Wt bf16 [256,K] ----------------
__global__ void k_cvtwt(const float* __restrict__ W, unsigned short* __restrict__ Wt, int K) {
    int id = blockIdx.x * blockDim.x + threadIdx.x;
    if (id >= K * HID) return;
    int n = id & (HID - 1), k = id >> 8;
    Wt[(size_t)n * K + k] = f2bf(W[(size_t)k * HID + n]);
}

// ---------------- aggregate x (32-wide, fp32 in, bf16 out) ----------------
__global__ void k_aggx(const float* __restrict__ x, const int* __restrict__ cnt,
                       const int* __restrict__ csr, const float* __restrict__ dis,
                       unsigned short* __restrict__ out, int N) {
    int node = blockIdx.x * 8 + (threadIdx.x >> 5);
    if (node >= N) return;
    int col = threadIdx.x & 31;
    float dn = dis[node];
    float acc = x[(size_t)node * FEAT + col] * dn * dn;
    int e = cnt[node]; if (e > CAP) e = CAP;
    const int* lst = &csr[(size_t)node * CAP];
    for (int i = 0; i < e; ++i) {
        int s = lst[i];
        acc += x[(size_t)s * FEAT + col] * (dis[s] * dn);
    }
    out[(size_t)node * FEAT + col] = f2bf(acc);
}

// ---------------- aggregate h (256-wide, bf16 in/out, no bias/relu) ----------------
__global__ void k_aggh(const unsigned short* __restrict__ h, const int* __restrict__ cnt,
                       const int* __restrict__ csr, const float* __restrict__ dis,
                       unsigned short* __restrict__ out, int N) {
    int wid = (int)((blockIdx.x * (size_t)blockDim.x + threadIdx.x) >> 6);
    if (wid >= N) return;
    int lane = threadIdx.x & 63;
    int c0 = lane * 4;

    float dn = dis[wid];
    float sw = dn * dn;
    ushort4 hv = *(const ushort4*)&h[(size_t)wid * HID + c0];
    float a0 = bf2f(hv.x) * sw, a1 = bf2f(hv.y) * sw;
    float a2 = bf2f(hv.z) * sw, a3 = bf2f(hv.w) * sw;

    int e = cnt[wid]; if (e > CAP) e = CAP;
    const int* lst = &csr[(size_t)wid * CAP];
    for (int i = 0; i < e; ++i) {
        int s = lst[i];
        float w = dis[s] * dn;
        ushort4 v = *(const ushort4*)&h[(size_t)s * HID + c0];
        a0 += w * bf2f(v.x); a1 += w * bf2f(v.y);
        a2 += w * bf2f(v.z); a3 += w * bf2f(v.w);
    }
    ushort4 o;
    o.x = f2bf(a0); o.y = f2bf(a1); o.z = f2bf(a2); o.w = f2bf(a3);
    *(ushort4*)&out[(size_t)wid * HID + c0] = o;
}

// ---------------- bf16 MFMA GEMM: C = relu(A[M,K] @ Wt[256,K]^T + bias) ----------------
// block 256 thr = 4 waves; block tile 32(M) x 256(N); wave tile 32 x 64.
// Frag layout (verified gfx950): A row = lane&15, k = (lane>>4)*8+j; B col = lane&15;
// C/D: col = lane&15, row = (lane>>4)*4 + reg.
__global__ void k_mmf(const unsigned short* __restrict__ A, const unsigned short* __restrict__ Wt,
                      const float* __restrict__ bias, unsigned short* __restrict__ C,
                      int M, int K) {
    int tid = threadIdx.x;
    int lane = tid & 63;
    int wid = tid >> 6;                 // n-block of 64
    int row0 = blockIdx.x * 32;
    int l15 = lane & 15;
    int lk = (lane >> 4) * 8;

    f32x4 acc[2][4];
#pragma unroll
    for (int mi = 0; mi < 2; ++mi)
#pragma unroll
        for (int ni = 0; ni < 4; ++ni) acc[mi][ni] = (f32x4){0.f, 0.f, 0.f, 0.f};

    for (int k0 = 0; k0 < K; k0 += 32) {
        bfrag fa[2];
#pragma unroll
        for (int mi = 0; mi < 2; ++mi) {
            int row = row0 + mi * 16 + l15;
            bfrag z = {0, 0, 0, 0, 0, 0, 0, 0};
            if (row < M) z = *(const bfrag*)&A[(size_t)row * K + k0 + lk];
            fa[mi] = z;
        }
        bfrag fb[4];
#pragma unroll
        for (int ni = 0; ni < 4; ++ni) {
            int colN = wid * 64 + ni * 16 + l15;
            fb[ni] = *(const bfrag*)&Wt[(size_t)colN * K + k0 + lk];
        }
#pragma unroll
        for (int mi = 0; mi < 2; ++mi)
#pragma unroll
            for (int ni = 0; ni < 4; ++ni)
                acc[mi][ni] = __builtin_amdgcn_mfma_f32_16x16x32_bf16(fa[mi], fb[ni], acc[mi][ni], 0, 0, 0);
    }

#pragma unroll
    for (int mi = 0; mi < 2; ++mi) {
#pragma unroll
        for (int ni = 0; ni < 4; ++ni) {
            int colN = wid * 64 + ni * 16 + l15;
            float b = bias[colN];
#pragma unroll
            for (int r = 0; r < 4; ++r) {
                int row = row0 + mi * 16 + (lane >> 4) * 4 + r;
                if (row < M) {
                    float v = fmaxf(acc[mi][ni][r] + b, 0.f);
                    C[(size_t)row * HID + colN] = f2bf(v);
                }
            }
        }
    }
}

// ---------------- segmented mean-pool (bf16 in, fp32 atomics) ----------------
__global__ void k_pool(const unsigned short* __restrict__ z, const int* __restrict__ batch,
                       float* __restrict__ pooled, int N) {
    int c = threadIdx.x;                 // 0..255
    int base = blockIdx.x * 128;
    if (base >= N) return;
    int end = base + 128; if (end > N) end = N;
    int cur = batch[base];
    float acc = 0.f;
    for (int n = base; n < end; ++n) {
        int g = batch[n];
        if (g != cur) {
            atomicAdd(&pooled[(size_t)cur * HID + c], acc);
            acc = 0.f; cur = g;
        }
        acc += bf2f(z[(size_t)n * HID + c]);
    }
    atomicAdd(&pooled[(size_t)cur * HID + c], acc);
}

// ---------------- head ----------------
__global__ void k_head(const float* __restrict__ pooled, const int* __restrict__ starts,
                       const float* __restrict__ Wf, const float* __restrict__ bf,
                       float* __restrict__ out) {
    int t = blockIdx.x * blockDim.x + threadIdx.x;
    if (t >= NGRAPH * 12) return;
    int g = t / 12, j = t % 12;
    float cntf = (float)(starts[g + 1] - starts[g]);
    float inv = 1.f / fmaxf(cntf, 1.f);
    float s = 0.f;
    for (int k = 0; k < HID; ++k) s += pooled[(size_t)g * HID + k] * Wf[k * 12 + j];
    s = s * inv + bf[j];
    if (j < 6) {
        out[g * 6 + j] = s;
    } else {
        float ls = fminf(fmaxf(s, -20.f), 2.f);
        out[NGRAPH * 6 + g * 6 + (j - 6)] = expf(ls);
    }
}

// ---------------- launch ----------------
extern "C" void kernel_launch(void* const* d_in, const int* in_sizes, int n_in,
                              void* d_out, int out_size, void* d_ws, size_t ws_size,
                              hipStream_t stream) {
    const float* x     = (const float*)d_in[0];
    const int*   ei    = (const int*)d_in[1];
    const int*   batch = (const int*)d_in[2];
    const float* W1    = (const float*)d_in[3];
    const float* b1    = (const float*)d_in[4];
    const float* W2    = (const float*)d_in[5];
    const float* b2    = (const float*)d_in[6];
    const float* Wf    = (const float*)d_in[7];
    const float* bfv   = (const float*)d_in[8];
    float* out = (float*)d_out;

    const int E = in_sizes[1] / 2;
    const int N = in_sizes[2];
    const int* srcp = ei;
    const int* dstp = ei + E;

    // workspace layout (128B-aligned segments)
    char* ws = (char*)d_ws;
    const size_t OFF_CTR    = 0;            // int[NN]            -> 200192
    const size_t OFF_POOLED = 200192;       // f32[64*256]        -> 265728
    const size_t ZERO_BYTES = 265728;
    const size_t OFF_STARTS = 265728;       // int[65]            -> 266240
    const size_t OFF_DIS    = 266240;       // f32[NN]            -> 466432
    const size_t OFF_W1T    = 466432;       // bf16[256*32]       -> 482816
    const size_t OFF_W2T    = 482816;       // bf16[256*256]      -> 613888
    const size_t OFF_CSR    = 613888;       // int[NN*CAP]        -> 13413888
    const size_t OFF_AGGX   = 13413888;     // bf16[NN*32]        -> 16613888
    const size_t OFF_H1     = 16613888;     // bf16[NN*256]       -> 42213888
    const size_t OFF_G      = 42213888;     // bf16[NN*256]       -> 67813888
    const size_t OFF_H2     = 67813888;     // bf16[NN*256]       -> 93413888

    int*            ctr    = (int*)(ws + OFF_CTR);
    float*          pooled = (float*)(ws + OFF_POOLED);
    int*            starts = (int*)(ws + OFF_STARTS);
    float*          dis    = (float*)(ws + OFF_DIS);
    unsigned short* W1t    = (unsigned short*)(ws + OFF_W1T);
    unsigned short* W2t    = (unsigned short*)(ws + OFF_W2T);
    int*            csr    = (int*)(ws + OFF_CSR);
    unsigned short* aggX   = (unsigned short*)(ws + OFF_AGGX);
    unsigned short* h1     = (unsigned short*)(ws + OFF_H1);
    unsigned short* g      = (unsigned short*)(ws + OFF_G);
    unsigned short* h2     = (unsigned short*)(ws + OFF_H2);

    hipMemsetAsync(ws, 0, ZERO_BYTES, stream);

    const int T = 256;
    k_gbounds<<<(N + T - 1) / T, T, 0, stream>>>(batch, starts, N);
    k_scatter<<<(E + T - 1) / T, T, 0, stream>>>(srcp, dstp, ctr, csr, E);
    k_dis<<<(N + T - 1) / T, T, 0, stream>>>(ctr, dis, N);
    k_cvtwt<<<(FEAT * HID + T - 1) / T, T, 0, stream>>>(W1, W1t, FEAT);
    k_cvtwt<<<(HID * HID + T - 1) / T, T, 0, stream>>>(W2, W2t, HID);

    // layer 1: aggX = A_hat x ; h1 = relu(aggX @ W1 + b1)
    k_aggx<<<(N + 7) / 8, T, 0, stream>>>(x, ctr, csr, dis, aggX, N);
    k_mmf<<<(N + 31) / 32, T, 0, stream>>>(aggX, W1t, b1, h1, N, FEAT);

    // layer 2: g = A_hat h1 ; h2 = relu(g @ W2 + b2)
    k_aggh<<<(N * 64 + T - 1) / T, T, 0, stream>>>(h1, ctr, csr, dis, g, N);
    k_mmf<<<(N + 31) / 32, T, 0, stream>>>(g, W2t, b2, h2, N, HID);

    // pool + head
    k_pool<<<(N + 127) / 128, T, 0, stream>>>(h2, batch, pooled, N);
    k_head<<<3, T, 0, stream>>>(pooled, starts, Wf, bfv, out);
}

// Round 5
// 211.881 us; speedup vs baseline: 3.2196x; 1.1427x over previous
//
#include <hip/hip_runtime.h>
#include <math.h>

#define NN 50000
#define FEAT 32
#define HID 256
#define NGRAPH 64
#define CAP 64

typedef __attribute__((ext_vector_type(8))) short bfrag;   // 8 bf16 (4 VGPRs)
typedef __attribute__((ext_vector_type(4))) float f32x4;   // MFMA accumulator

__device__ __forceinline__ float bf2f(unsigned short u) {
    union { unsigned int i; float f; } v; v.i = ((unsigned int)u) << 16; return v.f;
}
__device__ __forceinline__ unsigned short f2bf(float f) {
    union { float f; unsigned int i; } v; v.f = f;
    unsigned int r = v.i + 0x7fffu + ((v.i >> 16) & 1u);
    return (unsigned short)(r >> 16);
}

// ---------------- graph segment bounds (batch sorted) ----------------
__global__ void k_gbounds(const int* __restrict__ batch, int* __restrict__ starts, int N) {
    int i = blockIdx.x * blockDim.x + threadIdx.x;
    if (i >= N) return;
    int b = batch[i];
    int prev = (i == 0) ? -1 : batch[i - 1];
    if (b != prev) {
        for (int g = prev + 1; g <= b; ++g) starts[g] = i;
    }
    if (i == N - 1) {
        for (int g = b + 1; g <= NGRAPH; ++g) starts[g] = N;
    }
}

// ---------------- CSR-by-dst build; ctr ends up as in-degree ----------------
__global__ void k_scatter(const int* __restrict__ src, const int* __restrict__ dst,
                          int* __restrict__ counter, int* __restrict__ csr, int E) {
    int e = blockIdx.x * blockDim.x + threadIdx.x;
    if (e < E) {
        int d = dst[e];
        int p = atomicAdd(&counter[d], 1);
        if (p < CAP) csr[d * CAP + p] = src[e];
    }
}

__global__ void k_dis(const int* __restrict__ cnt, float* __restrict__ dis, int N) {
    int i = blockIdx.x * blockDim.x + threadIdx.x;
    if (i < N) dis[i] = 1.0f / sqrtf((float)(cnt[i] + 1));   // +1 = self-loop
}

// ---------------- x' = dis * x, cast bf16 ----------------
__global__ void k_prescale(const float* __restrict__ x, const float* __restrict__ dis,
                           unsigned short* __restrict__ xp, int N) {
    int id = blockIdx.x * blockDim.x + threadIdx.x;
    if (id < N * FEAT) xp[id] = f2bf(x[id] * dis[id >> 5]);
}

// ---------------- W [K,256] -> Wt bf16 [256,K] ----------------
__global__ void k_cvtwt(const float* __restrict__ W, unsigned short* __restrict__ Wt, int K) {
    int id = blockIdx.x * blockDim.x + threadIdx.x;
    if (id >= K * HID) return;
    int n = id & (HID - 1), k = id >> 8;
    Wt[(size_t)n * K + k] = f2bf(W[(size_t)k * HID + n]);
}

// ---------------- aggregate x' (32-wide bf16, pure gather-sum, x dn) ----------------
__global__ void k_aggx(const unsigned short* __restrict__ xp, const int* __restrict__ cnt,
                       const int* __restrict__ csr, const float* __restrict__ dis,
                       unsigned short* __restrict__ out, int N) {
    int node = blockIdx.x * 8 + (threadIdx.x >> 5);
    if (node >= N) return;
    int col = threadIdx.x & 31;
    float acc = bf2f(xp[(size_t)node * FEAT + col]);      // self term (pre-scaled)
    int e = cnt[node]; if (e > CAP) e = CAP;
    const int* lst = &csr[(size_t)node * CAP];
    int i = 0;
    for (; i + 4 <= e; i += 4) {
        int4 s4 = *(const int4*)&lst[i];
        float v0 = bf2f(xp[(size_t)s4.x * FEAT + col]);
        float v1 = bf2f(xp[(size_t)s4.y * FEAT + col]);
        float v2 = bf2f(xp[(size_t)s4.z * FEAT + col]);
        float v3 = bf2f(xp[(size_t)s4.w * FEAT + col]);
        acc += (v0 + v1) + (v2 + v3);
    }
    for (; i < e; ++i) acc += bf2f(xp[(size_t)lst[i] * FEAT + col]);
    out[(size_t)node * FEAT + col] = f2bf(acc * dis[node]);
}

// ---------------- aggregate h' (256-wide bf16, pure gather-sum, x dn) ----------------
__global__ void k_aggh(const unsigned short* __restrict__ h, const int* __restrict__ cnt,
                       const int* __restrict__ csr, const float* __restrict__ dis,
                       unsigned short* __restrict__ out, int N) {
    int wid = (int)((blockIdx.x * (size_t)blockDim.x + threadIdx.x) >> 6);
    if (wid >= N) return;
    int lane = threadIdx.x & 63;
    int c0 = lane * 4;

    ushort4 hv = *(const ushort4*)&h[(size_t)wid * HID + c0];   // self term (pre-scaled)
    float a0 = bf2f(hv.x), a1 = bf2f(hv.y), a2 = bf2f(hv.z), a3 = bf2f(hv.w);

    int e = cnt[wid]; if (e > CAP) e = CAP;
    const int* lst = &csr[(size_t)wid * CAP];
    int i = 0;
    for (; i + 4 <= e; i += 4) {
        int4 s4 = *(const int4*)&lst[i];
        ushort4 v0 = *(const ushort4*)&h[(size_t)s4.x * HID + c0];
        ushort4 v1 = *(const ushort4*)&h[(size_t)s4.y * HID + c0];
        ushort4 v2 = *(const ushort4*)&h[(size_t)s4.z * HID + c0];
        ushort4 v3 = *(const ushort4*)&h[(size_t)s4.w * HID + c0];
        a0 += (bf2f(v0.x) + bf2f(v1.x)) + (bf2f(v2.x) + bf2f(v3.x));
        a1 += (bf2f(v0.y) + bf2f(v1.y)) + (bf2f(v2.y) + bf2f(v3.y));
        a2 += (bf2f(v0.z) + bf2f(v1.z)) + (bf2f(v2.z) + bf2f(v3.z));
        a3 += (bf2f(v0.w) + bf2f(v1.w)) + (bf2f(v2.w) + bf2f(v3.w));
    }
    for (; i < e; ++i) {
        ushort4 v = *(const ushort4*)&h[(size_t)lst[i] * HID + c0];
        a0 += bf2f(v.x); a1 += bf2f(v.y); a2 += bf2f(v.z); a3 += bf2f(v.w);
    }
    float dn = dis[wid];
    ushort4 o;
    o.x = f2bf(a0 * dn); o.y = f2bf(a1 * dn); o.z = f2bf(a2 * dn); o.w = f2bf(a3 * dn);
    *(ushort4*)&out[(size_t)wid * HID + c0] = o;
}

// ---------------- bf16 MFMA GEMM: C = [scale*] relu(A[M,K] @ Wt^T + bias) ----------------
// block 256 thr = 4 waves; block tile 32(M) x 256(N); wave tile 32 x 64.
__global__ void k_mmf(const unsigned short* __restrict__ A, const unsigned short* __restrict__ Wt,
                      const float* __restrict__ bias, const float* __restrict__ scale,
                      unsigned short* __restrict__ C, int M, int K) {
    int tid = threadIdx.x;
    int lane = tid & 63;
    int wid = tid >> 6;                 // n-block of 64
    int row0 = blockIdx.x * 32;
    int l15 = lane & 15;
    int lk = (lane >> 4) * 8;

    f32x4 acc[2][4];
#pragma unroll
    for (int mi = 0; mi < 2; ++mi)
#pragma unroll
        for (int ni = 0; ni < 4; ++ni) acc[mi][ni] = (f32x4){0.f, 0.f, 0.f, 0.f};

    for (int k0 = 0; k0 < K; k0 += 32) {
        bfrag fa[2];
#pragma unroll
        for (int mi = 0; mi < 2; ++mi) {
            int row = row0 + mi * 16 + l15;
            bfrag z = {0, 0, 0, 0, 0, 0, 0, 0};
            if (row < M) z = *(const bfrag*)&A[(size_t)row * K + k0 + lk];
            fa[mi] = z;
        }
        bfrag fb[4];
#pragma unroll
        for (int ni = 0; ni < 4; ++ni) {
            int colN = wid * 64 + ni * 16 + l15;
            fb[ni] = *(const bfrag*)&Wt[(size_t)colN * K + k0 + lk];
        }
#pragma unroll
        for (int mi = 0; mi < 2; ++mi)
#pragma unroll
            for (int ni = 0; ni < 4; ++ni)
                acc[mi][ni] = __builtin_amdgcn_mfma_f32_16x16x32_bf16(fa[mi], fb[ni], acc[mi][ni], 0, 0, 0);
    }

#pragma unroll
    for (int mi = 0; mi < 2; ++mi) {
#pragma unroll
        for (int ni = 0; ni < 4; ++ni) {
            int colN = wid * 64 + ni * 16 + l15;
            float b = bias[colN];
#pragma unroll
            for (int r = 0; r < 4; ++r) {
                int row = row0 + mi * 16 + (lane >> 4) * 4 + r;
                if (row < M) {
                    float v = fmaxf(acc[mi][ni][r] + b, 0.f);
                    if (scale) v *= scale[row];
                    C[(size_t)row * HID + colN] = f2bf(v);
                }
            }
        }
    }
}

// ---------------- segmented mean-pool (bf16 in, fp32 atomics) ----------------
__global__ void k_pool(const unsigned short* __restrict__ z, const int* __restrict__ batch,
                       float* __restrict__ pooled, int N) {
    int c = threadIdx.x;                 // 0..255
    int base = blockIdx.x * 128;
    if (base >= N) return;
    int end = base + 128; if (end > N) end = N;
    int cur = batch[base];
    float acc = 0.f;
    for (int n = base; n < end; ++n) {
        int g = batch[n];
        if (g != cur) {
            atomicAdd(&pooled[(size_t)cur * HID + c], acc);
            acc = 0.f; cur = g;
        }
        acc += bf2f(z[(size_t)n * HID + c]);
    }
    atomicAdd(&pooled[(size_t)cur * HID + c], acc);
}

// ---------------- head ----------------
__global__ void k_head(const float* __restrict__ pooled, const int* __restrict__ starts,
                       const float* __restrict__ Wf, const float* __restrict__ bf,
                       float* __restrict__ out) {
    int t = blockIdx.x * blockDim.x + threadIdx.x;
    if (t >= NGRAPH * 12) return;
    int g = t / 12, j = t % 12;
    float cntf = (float)(starts[g + 1] - starts[g]);
    float inv = 1.f / fmaxf(cntf, 1.f);
    float s = 0.f;
    for (int k = 0; k < HID; ++k) s += pooled[(size_t)g * HID + k] * Wf[k * 12 + j];
    s = s * inv + bf[j];
    if (j < 6) {
        out[g * 6 + j] = s;
    } else {
        float ls = fminf(fmaxf(s, -20.f), 2.f);
        out[NGRAPH * 6 + g * 6 + (j - 6)] = expf(ls);
    }
}

// ---------------- launch ----------------
extern "C" void kernel_launch(void* const* d_in, const int* in_sizes, int n_in,
                              void* d_out, int out_size, void* d_ws, size_t ws_size,
                              hipStream_t stream) {
    const float* x     = (const float*)d_in[0];
    const int*   ei    = (const int*)d_in[1];
    const int*   batch = (const int*)d_in[2];
    const float* W1    = (const float*)d_in[3];
    const float* b1    = (const float*)d_in[4];
    const float* W2    = (const float*)d_in[5];
    const float* b2    = (const float*)d_in[6];
    const float* Wf    = (const float*)d_in[7];
    const float* bfv   = (const float*)d_in[8];
    float* out = (float*)d_out;

    const int E = in_sizes[1] / 2;
    const int N = in_sizes[2];
    const int* srcp = ei;
    const int* dstp = ei + E;

    // workspace layout
    char* ws = (char*)d_ws;
    const size_t OFF_CTR    = 0;            // int[NN]            -> 200192
    const size_t OFF_POOLED = 200192;       // f32[64*256]        -> 265728
    const size_t ZERO_BYTES = 265728;
    const size_t OFF_STARTS = 265728;       // int[65]            -> 266240
    const size_t OFF_DIS    = 266240;       // f32[NN]            -> 466432
    const size_t OFF_W1T    = 466432;       // bf16[256*32]       -> 482816
    const size_t OFF_W2T    = 482816;       // bf16[256*256]      -> 613888
    const size_t OFF_CSR    = 613888;       // int[NN*CAP]        -> 13413888
    const size_t OFF_XP     = 13413888;     // bf16[NN*32]        -> 16613888
    const size_t OFF_AGGX   = 16613888;     // bf16[NN*32]        -> 19813888
    const size_t OFF_H1     = 19813888;     // bf16[NN*256]       -> 45413888
    const size_t OFF_G      = 45413888;     // bf16[NN*256]       -> 71013888
    const size_t OFF_H2     = 71013888;     // bf16[NN*256]       -> 96613888

    int*            ctr    = (int*)(ws + OFF_CTR);
    float*          pooled = (float*)(ws + OFF_POOLED);
    int*            starts = (int*)(ws + OFF_STARTS);
    float*          dis    = (float*)(ws + OFF_DIS);
    unsigned short* W1t    = (unsigned short*)(ws + OFF_W1T);
    unsigned short* W2t    = (unsigned short*)(ws + OFF_W2T);
    int*            csr    = (int*)(ws + OFF_CSR);
    unsigned short* xp     = (unsigned short*)(ws + OFF_XP);
    unsigned short* aggX   = (unsigned short*)(ws + OFF_AGGX);
    unsigned short* h1     = (unsigned short*)(ws + OFF_H1);
    unsigned short* g      = (unsigned short*)(ws + OFF_G);
    unsigned short* h2     = (unsigned short*)(ws + OFF_H2);

    hipMemsetAsync(ws, 0, ZERO_BYTES, stream);

    const int T = 256;
    k_gbounds<<<(N + T - 1) / T, T, 0, stream>>>(batch, starts, N);
    k_scatter<<<(E + T - 1) / T, T, 0, stream>>>(srcp, dstp, ctr, csr, E);
    k_dis<<<(N + T - 1) / T, T, 0, stream>>>(ctr, dis, N);
    k_prescale<<<(N * FEAT + T - 1) / T, T, 0, stream>>>(x, dis, xp, N);
    k_cvtwt<<<(FEAT * HID + T - 1) / T, T, 0, stream>>>(W1, W1t, FEAT);
    k_cvtwt<<<(HID * HID + T - 1) / T, T, 0, stream>>>(W2, W2t, HID);

    // layer 1: aggX = dn*(sum x'[s] + x'[d]) ; h1 = dis * relu(aggX @ W1 + b1)
    k_aggx<<<(N + 7) / 8, T, 0, stream>>>(xp, ctr, csr, dis, aggX, N);
    k_mmf<<<(N + 31) / 32, T, 0, stream>>>(aggX, W1t, b1, dis, h1, N, FEAT);

    // layer 2: g = dn*(sum h1'[s] + h1'[d]) ; h2 = relu(g @ W2 + b2)
    k_aggh<<<(N * 64 + T - 1) / T, T, 0, stream>>>(h1, ctr, csr, dis, g, N);
    k_mmf<<<(N + 31) / 32, T, 0, stream>>>(g, W2t, b2, (const float*)nullptr, h2, N, HID);

    // pool + head
    k_pool<<<(N + 127) / 128, T, 0, stream>>>(h2, batch, pooled, N);
    k_head<<<3, T, 0, stream>>>(pooled, starts, Wf, bfv, out);
}

// Round 6
// 168.826 us; speedup vs baseline: 4.0407x; 1.2550x over previous
//
#include <hip/hip_runtime.h>
#include <math.h>

#define NN 50000
#define FEAT 32
#define HID 256
#define NGRAPH 64
#define CAP 64

typedef __attribute__((ext_vector_type(8))) short bfrag;   // 8 bf16 (4 VGPRs)
typedef __attribute__((ext_vector_type(4))) float f32x4;   // MFMA accumulator

__device__ __forceinline__ float bf2f(unsigned short u) {
    union { unsigned int i; float f; } v; v.i = ((unsigned int)u) << 16; return v.f;
}
__device__ __forceinline__ unsigned short f2bf(float f) {
    union { float f; unsigned int i; } v; v.f = f;
    unsigned int r = v.i + 0x7fffu + ((v.i >> 16) & 1u);
    return (unsigned short)(r >> 16);
}

// ---------------- graph segment bounds (batch sorted) ----------------
__global__ void k_gbounds(const int* __restrict__ batch, int* __restrict__ starts, int N) {
    int i = blockIdx.x * blockDim.x + threadIdx.x;
    if (i >= N) return;
    int b = batch[i];
    int prev = (i == 0) ? -1 : batch[i - 1];
    if (b != prev) {
        for (int g = prev + 1; g <= b; ++g) starts[g] = i;
    }
    if (i == N - 1) {
        for (int g = b + 1; g <= NGRAPH; ++g) starts[g] = N;
    }
}

// ---------------- CSR-by-dst build; ctr ends up as in-degree ----------------
__global__ void k_scatter(const int* __restrict__ src, const int* __restrict__ dst,
                          int* __restrict__ counter, int* __restrict__ csr, int E) {
    int e = blockIdx.x * blockDim.x + threadIdx.x;
    if (e < E) {
        int d = dst[e];
        int p = atomicAdd(&counter[d], 1);
        if (p < CAP) csr[d * CAP + p] = src[e];
    }
}

__global__ void k_dis(const int* __restrict__ cnt, float* __restrict__ dis, int N) {
    int i = blockIdx.x * blockDim.x + threadIdx.x;
    if (i < N) dis[i] = 1.0f / sqrtf((float)(cnt[i] + 1));   // +1 = self-loop
}

// ---------------- x' = dis * x, cast bf16 ----------------
__global__ void k_prescale(const float* __restrict__ x, const float* __restrict__ dis,
                           unsigned short* __restrict__ xp, int N) {
    int id = blockIdx.x * blockDim.x + threadIdx.x;
    if (id < N * FEAT) xp[id] = f2bf(x[id] * dis[id >> 5]);
}

// ---------------- W [K,256] -> packed fragment-major bf16 ----------------
// Wp[((nb*(K/32) + ks)*64 + lane)*8 + j] = bf16(W[k][n]),
//   n = nb*16 + (lane&15), k = ks*32 + (lane>>4)*8 + j.
// B-frag load in GEMM = 64 lanes x consecutive 16B -> one 1KB transaction.
__global__ void k_cvtwp(const float* __restrict__ W, unsigned short* __restrict__ Wp, int K) {
    int o = blockIdx.x * blockDim.x + threadIdx.x;
    if (o >= K * HID) return;
    int j    = o & 7;
    int lane = (o >> 3) & 63;
    int rest = o >> 9;
    int nst  = K >> 5;
    int ks   = rest & (nst - 1);
    int nb   = rest >> (K == 256 ? 3 : 0);     // rest / nst (nst pow2)
    if (K != 256) nb = rest / nst;             // safe generic
    int n = nb * 16 + (lane & 15);
    int k = ks * 32 + (lane >> 4) * 8 + j;
    Wp[o] = f2bf(W[(size_t)k * HID + n]);
}

// ---------------- aggregate x' (32-wide bf16, pure gather-sum, x dn) ----------------
__global__ void k_aggx(const unsigned short* __restrict__ xp, const int* __restrict__ cnt,
                       const int* __restrict__ csr, const float* __restrict__ dis,
                       unsigned short* __restrict__ out, int N) {
    int node = blockIdx.x * 8 + (threadIdx.x >> 5);
    if (node >= N) return;
    int col = threadIdx.x & 31;
    float acc = bf2f(xp[(size_t)node * FEAT + col]);      // self term (pre-scaled)
    int e = cnt[node]; if (e > CAP) e = CAP;
    const int* lst = &csr[(size_t)node * CAP];
    int i = 0;
    for (; i + 4 <= e; i += 4) {
        int4 s4 = *(const int4*)&lst[i];
        float v0 = bf2f(xp[(size_t)s4.x * FEAT + col]);
        float v1 = bf2f(xp[(size_t)s4.y * FEAT + col]);
        float v2 = bf2f(xp[(size_t)s4.z * FEAT + col]);
        float v3 = bf2f(xp[(size_t)s4.w * FEAT + col]);
        acc += (v0 + v1) + (v2 + v3);
    }
    for (; i < e; ++i) acc += bf2f(xp[(size_t)lst[i] * FEAT + col]);
    out[(size_t)node * FEAT + col] = f2bf(acc * dis[node]);
}

// ---------------- aggregate h' (256-wide bf16, pure gather-sum, x dn) ----------------
__global__ void k_aggh(const unsigned short* __restrict__ h, const int* __restrict__ cnt,
                       const int* __restrict__ csr, const float* __restrict__ dis,
                       unsigned short* __restrict__ out, int N) {
    int wid = (int)((blockIdx.x * (size_t)blockDim.x + threadIdx.x) >> 6);
    if (wid >= N) return;
    int lane = threadIdx.x & 63;
    int c0 = lane * 4;

    ushort4 hv = *(const ushort4*)&h[(size_t)wid * HID + c0];   // self term (pre-scaled)
    float a0 = bf2f(hv.x), a1 = bf2f(hv.y), a2 = bf2f(hv.z), a3 = bf2f(hv.w);

    int e = cnt[wid]; if (e > CAP) e = CAP;
    const int* lst = &csr[(size_t)wid * CAP];
    int i = 0;
    for (; i + 4 <= e; i += 4) {
        int4 s4 = *(const int4*)&lst[i];
        ushort4 v0 = *(const ushort4*)&h[(size_t)s4.x * HID + c0];
        ushort4 v1 = *(const ushort4*)&h[(size_t)s4.y * HID + c0];
        ushort4 v2 = *(const ushort4*)&h[(size_t)s4.z * HID + c0];
        ushort4 v3 = *(const ushort4*)&h[(size_t)s4.w * HID + c0];
        a0 += (bf2f(v0.x) + bf2f(v1.x)) + (bf2f(v2.x) + bf2f(v3.x));
        a1 += (bf2f(v0.y) + bf2f(v1.y)) + (bf2f(v2.y) + bf2f(v3.y));
        a2 += (bf2f(v0.z) + bf2f(v1.z)) + (bf2f(v2.z) + bf2f(v3.z));
        a3 += (bf2f(v0.w) + bf2f(v1.w)) + (bf2f(v2.w) + bf2f(v3.w));
    }
    for (; i < e; ++i) {
        ushort4 v = *(const ushort4*)&h[(size_t)lst[i] * HID + c0];
        a0 += bf2f(v.x); a1 += bf2f(v.y); a2 += bf2f(v.z); a3 += bf2f(v.w);
    }
    float dn = dis[wid];
    ushort4 o;
    o.x = f2bf(a0 * dn); o.y = f2bf(a1 * dn); o.z = f2bf(a2 * dn); o.w = f2bf(a3 * dn);
    *(ushort4*)&out[(size_t)wid * HID + c0] = o;
}

// ---------------- bf16 MFMA GEMM: C = [scale*] relu(A[M,K] @ W + bias) ----------------
// 256 thr = 4 waves. Block tile 64(M) x 256(N, full HID); wave tile 64x64.
// A staged in LDS (coalesced, padded pitch); B from fragment-packed Wp (coalesced);
// swapped-operand MFMA (D^T) + LDS transpose -> fully coalesced C stores.
__global__ __launch_bounds__(256, 4)
void k_mmf(const unsigned short* __restrict__ A, const unsigned short* __restrict__ Wp,
           const float* __restrict__ bias, const float* __restrict__ scale,
           unsigned short* __restrict__ C, int M, int K, int lgK) {
    __shared__ unsigned short lds[64 * 264];   // A-tile (pitch K+8) then C-tile (pitch 264)
    int tid  = threadIdx.x;
    int lane = tid & 63;
    int wid  = tid >> 6;          // 0..3 : N-quadrant of 64 cols
    int l15  = lane & 15;
    int lq   = lane >> 4;         // 0..3
    int row0 = blockIdx.x * 64;

    // ---- stage A-tile [64][K] -> LDS, pitch P = K+8 shorts (bank skew) ----
    const int P = K + 8;
    int iters = (64 * K) >> 11;   // 16B per thread per iter
    for (int it = 0; it < iters; ++it) {
        int flat = (it * 256 + tid) * 8;
        int row = flat >> lgK;
        int col = flat & (K - 1);
        bfrag v = {0, 0, 0, 0, 0, 0, 0, 0};
        int gr = row0 + row;
        if (gr < M) v = *(const bfrag*)&A[(size_t)gr * K + col];
        *(bfrag*)&lds[row * P + col] = v;
    }
    __syncthreads();

    // ---- K loop ----
    int nsteps = K >> 5;
    f32x4 acc[4][4];
#pragma unroll
    for (int mi = 0; mi < 4; ++mi)
#pragma unroll
        for (int ni = 0; ni < 4; ++ni) acc[mi][ni] = (f32x4){0.f, 0.f, 0.f, 0.f};

    for (int ks = 0; ks < nsteps; ++ks) {
        bfrag fb[4];
#pragma unroll
        for (int ni = 0; ni < 4; ++ni) {
            size_t off = (((size_t)(wid * 4 + ni) * nsteps + ks) * 64 + lane) * 8;
            fb[ni] = *(const bfrag*)&Wp[off];
        }
        bfrag fa[4];
        int koff = ks * 32 + lq * 8;
#pragma unroll
        for (int mi = 0; mi < 4; ++mi)
            fa[mi] = *(const bfrag*)&lds[(mi * 16 + l15) * P + koff];
#pragma unroll
        for (int mi = 0; mi < 4; ++mi)
#pragma unroll
            for (int ni = 0; ni < 4; ++ni)
                acc[mi][ni] = __builtin_amdgcn_mfma_f32_16x16x32_bf16(fb[ni], fa[mi], acc[mi][ni], 0, 0, 0);
        // D^T layout: lane&15 -> M-row (block-local mi*16+l15),
        //             (lane>>4)*4+reg -> N-col ((wid*4+ni)*16 + lq*4 + reg)
    }

    // ---- epilogue: bias (+scale) -> bf16 -> LDS [64][256] pitch 264 -> coalesced copy ----
    float4 bv[4];
#pragma unroll
    for (int ni = 0; ni < 4; ++ni)
        bv[ni] = *(const float4*)&bias[(wid * 4 + ni) * 16 + lq * 4];
    float sv[4];
    if (scale) {
#pragma unroll
        for (int mi = 0; mi < 4; ++mi) {
            int gr = row0 + mi * 16 + l15;
            sv[mi] = (gr < M) ? scale[gr] : 0.f;
        }
    } else {
        sv[0] = sv[1] = sv[2] = sv[3] = 1.f;
    }

    __syncthreads();   // all fa reads done before overwriting LDS with C
#pragma unroll
    for (int mi = 0; mi < 4; ++mi) {
#pragma unroll
        for (int ni = 0; ni < 4; ++ni) {
            const float* bp = (const float*)&bv[ni];
            ushort4 o;
            o.x = f2bf(fmaxf(acc[mi][ni][0] + bp[0], 0.f) * sv[mi]);
            o.y = f2bf(fmaxf(acc[mi][ni][1] + bp[1], 0.f) * sv[mi]);
            o.z = f2bf(fmaxf(acc[mi][ni][2] + bp[2], 0.f) * sv[mi]);
            o.w = f2bf(fmaxf(acc[mi][ni][3] + bp[3], 0.f) * sv[mi]);
            *(ushort4*)&lds[(mi * 16 + l15) * 264 + (wid * 4 + ni) * 16 + lq * 4] = o;
        }
    }
    __syncthreads();

#pragma unroll
    for (int i = 0; i < 8; ++i) {
        int F = (i * 256 + tid) * 8;     // short index in 64x256 logical tile
        int row = F >> 8;
        int col = F & 255;
        int gr = row0 + row;
        if (gr < M) {
            bfrag v = *(const bfrag*)&lds[row * 264 + col];
            *(bfrag*)&C[(size_t)gr * HID + col] = v;
        }
    }
}

// ---------------- segmented mean-pool (bf16 in, fp32 atomics) ----------------
__global__ void k_pool(const unsigned short* __restrict__ z, const int* __restrict__ batch,
                       float* __restrict__ pooled, int N) {
    int c = threadIdx.x;                 // 0..255
    int base = blockIdx.x * 128;
    if (base >= N) return;
    int end = base + 128; if (end > N) end = N;
    int cur = batch[base];
    float acc = 0.f;
    for (int n = base; n < end; ++n) {
        int g = batch[n];
        if (g != cur) {
            atomicAdd(&pooled[(size_t)cur * HID + c], acc);
            acc = 0.f; cur = g;
        }
        acc += bf2f(z[(size_t)n * HID + c]);
    }
    atomicAdd(&pooled[(size_t)cur * HID + c], acc);
}

// ---------------- head ----------------
__global__ void k_head(const float* __restrict__ pooled, const int* __restrict__ starts,
                       const float* __restrict__ Wf, const float* __restrict__ bf,
                       float* __restrict__ out) {
    int t = blockIdx.x * blockDim.x + threadIdx.x;
    if (t >= NGRAPH * 12) return;
    int g = t / 12, j = t % 12;
    float cntf = (float)(starts[g + 1] - starts[g]);
    float inv = 1.f / fmaxf(cntf, 1.f);
    float s = 0.f;
    for (int k = 0; k < HID; ++k) s += pooled[(size_t)g * HID + k] * Wf[k * 12 + j];
    s = s * inv + bf[j];
    if (j < 6) {
        out[g * 6 + j] = s;
    } else {
        float ls = fminf(fmaxf(s, -20.f), 2.f);
        out[NGRAPH * 6 + g * 6 + (j - 6)] = expf(ls);
    }
}

// ---------------- launch ----------------
extern "C" void kernel_launch(void* const* d_in, const int* in_sizes, int n_in,
                              void* d_out, int out_size, void* d_ws, size_t ws_size,
                              hipStream_t stream) {
    const float* x     = (const float*)d_in[0];
    const int*   ei    = (const int*)d_in[1];
    const int*   batch = (const int*)d_in[2];
    const float* W1    = (const float*)d_in[3];
    const float* b1    = (const float*)d_in[4];
    const float* W2    = (const float*)d_in[5];
    const float* b2    = (const float*)d_in[6];
    const float* Wf    = (const float*)d_in[7];
    const float* bfv   = (const float*)d_in[8];
    float* out = (float*)d_out;

    const int E = in_sizes[1] / 2;
    const int N = in_sizes[2];
    const int* srcp = ei;
    const int* dstp = ei + E;

    // workspace layout
    char* ws = (char*)d_ws;
    const size_t OFF_CTR    = 0;            // int[NN]            -> 200192
    const size_t OFF_POOLED = 200192;       // f32[64*256]        -> 265728
    const size_t ZERO_BYTES = 265728;
    const size_t OFF_STARTS = 265728;       // int[65]            -> 266240
    const size_t OFF_DIS    = 266240;       // f32[NN]            -> 466432
    const size_t OFF_W1P    = 466432;       // bf16[32*256]       -> 482816
    const size_t OFF_W2P    = 482816;       // bf16[256*256]      -> 613888
    const size_t OFF_CSR    = 613888;       // int[NN*CAP]        -> 13413888
    const size_t OFF_XP     = 13413888;     // bf16[NN*32]        -> 16613888
    const size_t OFF_AGGX   = 16613888;     // bf16[NN*32]        -> 19813888
    const size_t OFF_H1     = 19813888;     // bf16[NN*256]       -> 45413888
    const size_t OFF_G      = 45413888;     // bf16[NN*256]       -> 71013888
    const size_t OFF_H2     = 71013888;     // bf16[NN*256]       -> 96613888

    int*            ctr    = (int*)(ws + OFF_CTR);
    float*          pooled = (float*)(ws + OFF_POOLED);
    int*            starts = (int*)(ws + OFF_STARTS);
    float*          dis    = (float*)(ws + OFF_DIS);
    unsigned short* W1p    = (unsigned short*)(ws + OFF_W1P);
    unsigned short* W2p    = (unsigned short*)(ws + OFF_W2P);
    int*            csr    = (int*)(ws + OFF_CSR);
    unsigned short* xp     = (unsigned short*)(ws + OFF_XP);
    unsigned short* aggX   = (unsigned short*)(ws + OFF_AGGX);
    unsigned short* h1     = (unsigned short*)(ws + OFF_H1);
    unsigned short* g      = (unsigned short*)(ws + OFF_G);
    unsigned short* h2     = (unsigned short*)(ws + OFF_H2);

    hipMemsetAsync(ws, 0, ZERO_BYTES, stream);

    const int T = 256;
    k_gbounds<<<(N + T - 1) / T, T, 0, stream>>>(batch, starts, N);
    k_scatter<<<(E + T - 1) / T, T, 0, stream>>>(srcp, dstp, ctr, csr, E);
    k_dis<<<(N + T - 1) / T, T, 0, stream>>>(ctr, dis, N);
    k_prescale<<<(N * FEAT + T - 1) / T, T, 0, stream>>>(x, dis, xp, N);
    k_cvtwp<<<(FEAT * HID + T - 1) / T, T, 0, stream>>>(W1, W1p, FEAT);
    k_cvtwp<<<(HID * HID + T - 1) / T, T, 0, stream>>>(W2, W2p, HID);

    // layer 1: aggX = dn*(sum x'[s] + x'[d]) ; h1 = dis * relu(aggX @ W1 + b1)
    k_aggx<<<(N + 7) / 8, T, 0, stream>>>(xp, ctr, csr, dis, aggX, N);
    k_mmf<<<(N + 63) / 64, T, 0, stream>>>(aggX, W1p, b1, dis, h1, N, FEAT, 5);

    // layer 2: g = dn*(sum h1'[s] + h1'[d]) ; h2 = relu(g @ W2 + b2)
    k_aggh<<<(N * 64 + T - 1) / T, T, 0, stream>>>(h1, ctr, csr, dis, g, N);
    k_mmf<<<(N + 63) / 64, T, 0, stream>>>(g, W2p, b2, (const float*)nullptr, h2, N, HID, 8);

    // pool + head
    k_pool<<<(N + 127) / 128, T, 0, stream>>>(h2, batch, pooled, N);
    k_head<<<3, T, 0, stream>>>(pooled, starts, Wf, bfv, out);
}

// Round 7
// 167.865 us; speedup vs baseline: 4.0638x; 1.0057x over previous
//
#include <hip/hip_runtime.h>
#include <math.h>

#define NN 50000
#define FEAT 32
#define HID 256
#define NGRAPH 64
#define CAP 64

typedef __attribute__((ext_vector_type(8))) short bfrag;   // 8 bf16 (4 VGPRs)
typedef __attribute__((ext_vector_type(4))) float f32x4;   // MFMA accumulator

__device__ __forceinline__ float bf2f(unsigned short u) {
    union { unsigned int i; float f; } v; v.i = ((unsigned int)u) << 16; return v.f;
}
__device__ __forceinline__ unsigned short f2bf(float f) {
    union { float f; unsigned int i; } v; v.f = f;
    unsigned int r = v.i + 0x7fffu + ((v.i >> 16) & 1u);
    return (unsigned short)(r >> 16);
}

// ---------------- zero the atomics region (ctr + pooled) ----------------
__global__ void k_zero(float4* __restrict__ p, int n16) {
    int i = blockIdx.x * blockDim.x + threadIdx.x;
    if (i < n16) p[i] = make_float4(0.f, 0.f, 0.f, 0.f);
}

// ---------------- graph segment bounds (batch sorted) ----------------
__global__ void k_gbounds(const int* __restrict__ batch, int* __restrict__ starts, int N) {
    int i = blockIdx.x * blockDim.x + threadIdx.x;
    if (i >= N) return;
    int b = batch[i];
    int prev = (i == 0) ? -1 : batch[i - 1];
    if (b != prev) {
        for (int g = prev + 1; g <= b; ++g) starts[g] = i;
    }
    if (i == N - 1) {
        for (int g = b + 1; g <= NGRAPH; ++g) starts[g] = N;
    }
}

// ---------------- CSR-by-dst build; ctr ends up as in-degree ----------------
__global__ void k_scatter(const int* __restrict__ src, const int* __restrict__ dst,
                          int* __restrict__ counter, int* __restrict__ csr, int E) {
    int e = blockIdx.x * blockDim.x + threadIdx.x;
    if (e < E) {
        int d = dst[e];
        int p = atomicAdd(&counter[d], 1);
        if (p < CAP) csr[d * CAP + p] = src[e];
    }
}

__global__ void k_dis(const int* __restrict__ cnt, float* __restrict__ dis, int N) {
    int i = blockIdx.x * blockDim.x + threadIdx.x;
    if (i < N) dis[i] = 1.0f / sqrtf((float)(cnt[i] + 1));   // +1 = self-loop
}

// ---------------- x' = dis * x, cast bf16 ----------------
__global__ void k_prescale(const float* __restrict__ x, const float* __restrict__ dis,
                           unsigned short* __restrict__ xp, int N) {
    int id = blockIdx.x * blockDim.x + threadIdx.x;
    if (id < N * FEAT) xp[id] = f2bf(x[id] * dis[id >> 5]);
}

// ---------------- W [K,256] -> packed fragment-major bf16 ----------------
// Wp[((nb*(K/32) + ks)*64 + lane)*8 + j] = bf16(W[k][n]),
//   n = nb*16 + (lane&15), k = ks*32 + (lane>>4)*8 + j.
__global__ void k_cvtwp(const float* __restrict__ W, unsigned short* __restrict__ Wp, int K) {
    int o = blockIdx.x * blockDim.x + threadIdx.x;
    if (o >= K * HID) return;
    int j    = o & 7;
    int lane = (o >> 3) & 63;
    int rest = o >> 9;
    int nst  = K >> 5;
    int ks   = rest & (nst - 1);
    int nb   = rest / nst;
    int n = nb * 16 + (lane & 15);
    int k = ks * 32 + (lane >> 4) * 8 + j;
    Wp[o] = f2bf(W[(size_t)k * HID + n]);
}

// ---------------- aggregate x' (32-wide bf16, pure gather-sum, x dn) ----------------
__global__ void k_aggx(const unsigned short* __restrict__ xp, const int* __restrict__ cnt,
                       const int* __restrict__ csr, const float* __restrict__ dis,
                       unsigned short* __restrict__ out, int N) {
    int node = blockIdx.x * 8 + (threadIdx.x >> 5);
    if (node >= N) return;
    int col = threadIdx.x & 31;
    float acc = bf2f(xp[(size_t)node * FEAT + col]);      // self term (pre-scaled)
    int e = cnt[node]; if (e > CAP) e = CAP;
    const int* lst = &csr[(size_t)node * CAP];
    int i = 0;
    for (; i + 4 <= e; i += 4) {
        int4 s4 = *(const int4*)&lst[i];
        float v0 = bf2f(xp[(size_t)s4.x * FEAT + col]);
        float v1 = bf2f(xp[(size_t)s4.y * FEAT + col]);
        float v2 = bf2f(xp[(size_t)s4.z * FEAT + col]);
        float v3 = bf2f(xp[(size_t)s4.w * FEAT + col]);
        acc += (v0 + v1) + (v2 + v3);
    }
    for (; i < e; ++i) acc += bf2f(xp[(size_t)lst[i] * FEAT + col]);
    out[(size_t)node * FEAT + col] = f2bf(acc * dis[node]);
}

// ---------------- aggregate h' (256-wide bf16, pure gather-sum, x dn) ----------------
__global__ void k_aggh(const unsigned short* __restrict__ h, const int* __restrict__ cnt,
                       const int* __restrict__ csr, const float* __restrict__ dis,
                       unsigned short* __restrict__ out, int N) {
    int wid = (int)((blockIdx.x * (size_t)blockDim.x + threadIdx.x) >> 6);
    if (wid >= N) return;
    int lane = threadIdx.x & 63;
    int c0 = lane * 4;

    ushort4 hv = *(const ushort4*)&h[(size_t)wid * HID + c0];   // self term (pre-scaled)
    float a0 = bf2f(hv.x), a1 = bf2f(hv.y), a2 = bf2f(hv.z), a3 = bf2f(hv.w);

    int e = cnt[wid]; if (e > CAP) e = CAP;
    const int* lst = &csr[(size_t)wid * CAP];
    int i = 0;
    for (; i + 4 <= e; i += 4) {
        int4 s4 = *(const int4*)&lst[i];
        ushort4 v0 = *(const ushort4*)&h[(size_t)s4.x * HID + c0];
        ushort4 v1 = *(const ushort4*)&h[(size_t)s4.y * HID + c0];
        ushort4 v2 = *(const ushort4*)&h[(size_t)s4.z * HID + c0];
        ushort4 v3 = *(const ushort4*)&h[(size_t)s4.w * HID + c0];
        a0 += (bf2f(v0.x) + bf2f(v1.x)) + (bf2f(v2.x) + bf2f(v3.x));
        a1 += (bf2f(v0.y) + bf2f(v1.y)) + (bf2f(v2.y) + bf2f(v3.y));
        a2 += (bf2f(v0.z) + bf2f(v1.z)) + (bf2f(v2.z) + bf2f(v3.z));
        a3 += (bf2f(v0.w) + bf2f(v1.w)) + (bf2f(v2.w) + bf2f(v3.w));
    }
    for (; i < e; ++i) {
        ushort4 v = *(const ushort4*)&h[(size_t)lst[i] * HID + c0];
        a0 += bf2f(v.x); a1 += bf2f(v.y); a2 += bf2f(v.z); a3 += bf2f(v.w);
    }
    float dn = dis[wid];
    ushort4 o;
    o.x = f2bf(a0 * dn); o.y = f2bf(a1 * dn); o.z = f2bf(a2 * dn); o.w = f2bf(a3 * dn);
    *(ushort4*)&out[(size_t)wid * HID + c0] = o;
}

// ---------------- bf16 MFMA GEMM: C = [scale*] relu(A[M,K] @ W + bias) ----------------
// 256 thr = 4 waves. Block tile 64(M) x 256(N, full HID); wave tile 64x64.
__global__ __launch_bounds__(256, 4)
void k_mmf(const unsigned short* __restrict__ A, const unsigned short* __restrict__ Wp,
           const float* __restrict__ bias, const float* __restrict__ scale,
           unsigned short* __restrict__ C, int M, int K, int lgK) {
    __shared__ unsigned short lds[64 * 264];   // A-tile (pitch K+8) then C-tile (pitch 264)
    int tid  = threadIdx.x;
    int lane = tid & 63;
    int wid  = tid >> 6;          // 0..3 : N-quadrant of 64 cols
    int l15  = lane & 15;
    int lq   = lane >> 4;         // 0..3
    int row0 = blockIdx.x * 64;

    // ---- stage A-tile [64][K] -> LDS, pitch P = K+8 shorts (bank skew) ----
    const int P = K + 8;
    int iters = (64 * K) >> 11;   // 16B per thread per iter
    for (int it = 0; it < iters; ++it) {
        int flat = (it * 256 + tid) * 8;
        int row = flat >> lgK;
        int col = flat & (K - 1);
        bfrag v = {0, 0, 0, 0, 0, 0, 0, 0};
        int gr = row0 + row;
        if (gr < M) v = *(const bfrag*)&A[(size_t)gr * K + col];
        *(bfrag*)&lds[row * P + col] = v;
    }
    __syncthreads();

    // ---- K loop ----
    int nsteps = K >> 5;
    f32x4 acc[4][4];
#pragma unroll
    for (int mi = 0; mi < 4; ++mi)
#pragma unroll
        for (int ni = 0; ni < 4; ++ni) acc[mi][ni] = (f32x4){0.f, 0.f, 0.f, 0.f};

    for (int ks = 0; ks < nsteps; ++ks) {
        bfrag fb[4];
#pragma unroll
        for (int ni = 0; ni < 4; ++ni) {
            size_t off = (((size_t)(wid * 4 + ni) * nsteps + ks) * 64 + lane) * 8;
            fb[ni] = *(const bfrag*)&Wp[off];
        }
        bfrag fa[4];
        int koff = ks * 32 + lq * 8;
#pragma unroll
        for (int mi = 0; mi < 4; ++mi)
            fa[mi] = *(const bfrag*)&lds[(mi * 16 + l15) * P + koff];
#pragma unroll
        for (int mi = 0; mi < 4; ++mi)
#pragma unroll
            for (int ni = 0; ni < 4; ++ni)
                acc[mi][ni] = __builtin_amdgcn_mfma_f32_16x16x32_bf16(fb[ni], fa[mi], acc[mi][ni], 0, 0, 0);
        // D^T: lane&15 -> M-row (mi*16+l15), (lane>>4)*4+reg -> N-col ((wid*4+ni)*16+lq*4+reg)
    }

    // ---- epilogue: bias (+scale) -> bf16 -> LDS [64][256] pitch 264 -> coalesced copy ----
    float4 bv[4];
#pragma unroll
    for (int ni = 0; ni < 4; ++ni)
        bv[ni] = *(const float4*)&bias[(wid * 4 + ni) * 16 + lq * 4];
    float sv[4];
    if (scale) {
#pragma unroll
        for (int mi = 0; mi < 4; ++mi) {
            int gr = row0 + mi * 16 + l15;
            sv[mi] = (gr < M) ? scale[gr] : 0.f;
        }
    } else {
        sv[0] = sv[1] = sv[2] = sv[3] = 1.f;
    }

    __syncthreads();   // all fa reads done before overwriting LDS with C
#pragma unroll
    for (int mi = 0; mi < 4; ++mi) {
#pragma unroll
        for (int ni = 0; ni < 4; ++ni) {
            const float* bp = (const float*)&bv[ni];
            ushort4 o;
            o.x = f2bf(fmaxf(acc[mi][ni][0] + bp[0], 0.f) * sv[mi]);
            o.y = f2bf(fmaxf(acc[mi][ni][1] + bp[1], 0.f) * sv[mi]);
            o.z = f2bf(fmaxf(acc[mi][ni][2] + bp[2], 0.f) * sv[mi]);
            o.w = f2bf(fmaxf(acc[mi][ni][3] + bp[3], 0.f) * sv[mi]);
            *(ushort4*)&lds[(mi * 16 + l15) * 264 + (wid * 4 + ni) * 16 + lq * 4] = o;
        }
    }
    __syncthreads();

#pragma unroll
    for (int i = 0; i < 8; ++i) {
        int F = (i * 256 + tid) * 8;     // short index in 64x256 logical tile
        int row = F >> 8;
        int col = F & 255;
        int gr = row0 + row;
        if (gr < M) {
            bfrag v = *(const bfrag*)&lds[row * 264 + col];
            *(bfrag*)&C[(size_t)gr * HID + col] = v;
        }
    }
}

// ---------------- segmented mean-pool (bf16 in, fp32 atomics) ----------------
__global__ void k_pool(const unsigned short* __restrict__ z, const int* __restrict__ batch,
                       float* __restrict__ pooled, int N) {
    int c = threadIdx.x;                 // 0..255
    int base = blockIdx.x * 128;
    if (base >= N) return;
    int end = base + 128; if (end > N) end = N;
    int cur = batch[base];
    float acc = 0.f;
    for (int n = base; n < end; ++n) {
        int g = batch[n];
        if (g != cur) {
            atomicAdd(&pooled[(size_t)cur * HID + c], acc);
            acc = 0.f; cur = g;
        }
        acc += bf2f(z[(size_t)n * HID + c]);
    }
    atomicAdd(&pooled[(size_t)cur * HID + c], acc);
}

// ---------------- head ----------------
__global__ void k_head(const float* __restrict__ pooled, const int* __restrict__ starts,
                       const float* __restrict__ Wf, const float* __restrict__ bf,
                       float* __restrict__ out) {
    int t = blockIdx.x * blockDim.x + threadIdx.x;
    if (t >= NGRAPH * 12) return;
    int g = t / 12, j = t % 12;
    float cntf = (float)(starts[g + 1] - starts[g]);
    float inv = 1.f / fmaxf(cntf, 1.f);
    float s = 0.f;
    for (int k = 0; k < HID; ++k) s += pooled[(size_t)g * HID + k] * Wf[k * 12 + j];
    s = s * inv + bf[j];
    if (j < 6) {
        out[g * 6 + j] = s;
    } else {
        float ls = fminf(fmaxf(s, -20.f), 2.f);
        out[NGRAPH * 6 + g * 6 + (j - 6)] = expf(ls);
    }
}

// ---------------- launch ----------------
extern "C" void kernel_launch(void* const* d_in, const int* in_sizes, int n_in,
                              void* d_out, int out_size, void* d_ws, size_t ws_size,
                              hipStream_t stream) {
    const float* x     = (const float*)d_in[0];
    const int*   ei    = (const int*)d_in[1];
    const int*   batch = (const int*)d_in[2];
    const float* W1    = (const float*)d_in[3];
    const float* b1    = (const float*)d_in[4];
    const float* W2    = (const float*)d_in[5];
    const float* b2    = (const float*)d_in[6];
    const float* Wf    = (const float*)d_in[7];
    const float* bfv   = (const float*)d_in[8];
    float* out = (float*)d_out;

    const int E = in_sizes[1] / 2;
    const int N = in_sizes[2];
    const int* srcp = ei;
    const int* dstp = ei + E;

    // workspace layout
    char* ws = (char*)d_ws;
    const size_t OFF_CTR    = 0;            // int[NN]            -> 200192
    const size_t OFF_POOLED = 200192;       // f32[64*256]        -> 265728
    const size_t ZERO_BYTES = 265728;
    const size_t OFF_STARTS = 265728;       // int[65]            -> 266240
    const size_t OFF_DIS    = 266240;       // f32[NN]            -> 466432
    const size_t OFF_W1P    = 466432;       // bf16[32*256]       -> 482816
    const size_t OFF_W2P    = 482816;       // bf16[256*256]      -> 613888
    const size_t OFF_CSR    = 613888;       // int[NN*CAP]        -> 13413888
    const size_t OFF_XP     = 13413888;     // bf16[NN*32]        -> 16613888
    const size_t OFF_AGGX   = 16613888;     // bf16[NN*32]        -> 19813888
    const size_t OFF_H1     = 19813888;     // bf16[NN*256]       -> 45413888
    const size_t OFF_G      = 45413888;     // bf16[NN*256]       -> 71013888
    const size_t OFF_H2     = 71013888;     // bf16[NN*256]       -> 96613888

    int*            ctr    = (int*)(ws + OFF_CTR);
    float*          pooled = (float*)(ws + OFF_POOLED);
    int*            starts = (int*)(ws + OFF_STARTS);
    float*          dis    = (float*)(ws + OFF_DIS);
    unsigned short* W1p    = (unsigned short*)(ws + OFF_W1P);
    unsigned short* W2p    = (unsigned short*)(ws + OFF_W2P);
    int*            csr    = (int*)(ws + OFF_CSR);
    unsigned short* xp     = (unsigned short*)(ws + OFF_XP);
    unsigned short* aggX   = (unsigned short*)(ws + OFF_AGGX);
    unsigned short* h1     = (unsigned short*)(ws + OFF_H1);
    unsigned short* g      = (unsigned short*)(ws + OFF_G);
    unsigned short* h2     = (unsigned short*)(ws + OFF_H2);

    const int T = 256;
    k_zero<<<(265728 / 16 + T - 1) / T, T, 0, stream>>>((float4*)ws, 265728 / 16);
    k_gbounds<<<(N + T - 1) / T, T, 0, stream>>>(batch, starts, N);
    k_scatter<<<(E + T - 1) / T, T, 0, stream>>>(srcp, dstp, ctr, csr, E);
    k_dis<<<(N + T - 1) / T, T, 0, stream>>>(ctr, dis, N);
    k_prescale<<<(N * FEAT + T - 1) / T, T, 0, stream>>>(x, dis, xp, N);
    k_cvtwp<<<(FEAT * HID + T - 1) / T, T, 0, stream>>>(W1, W1p, FEAT);
    k_cvtwp<<<(HID * HID + T - 1) / T, T, 0, stream>>>(W2, W2p, HID);

    // layer 1: aggX = dn*(sum x'[s] + x'[d]) ; h1 = dis * relu(aggX @ W1 + b1)
    k_aggx<<<(N + 7) / 8, T, 0, stream>>>(xp, ctr, csr, dis, aggX, N);
    k_mmf<<<(N + 63) / 64, T, 0, stream>>>(aggX, W1p, b1, dis, h1, N, FEAT, 5);

    // layer 2: g = dn*(sum h1'[s] + h1'[d]) ; h2 = relu(g @ W2 + b2)
    k_aggh<<<(N * 64 + T - 1) / T, T, 0, stream>>>(h1, ctr, csr, dis, g, N);
    k_mmf<<<(N + 63) / 64, T, 0, stream>>>(g, W2p, b2, (const float*)nullptr, h2, N, HID, 8);

    // pool + head
    k_pool<<<(N + 127) / 128, T, 0, stream>>>(h2, batch, pooled, N);
    k_head<<<3, T, 0, stream>>>(pooled, starts, Wf, bfv, out);
}

// Round 8
// 128.374 us; speedup vs baseline: 5.3139x; 1.3076x over previous
//
#include <hip/hip_runtime.h>
#include <math.h>

#define NN 50000
#define FEAT 32
#define HID 256
#define NGRAPH 64
#define CAP 64

typedef __attribute__((ext_vector_type(8))) short bfrag;   // 8 bf16 (4 VGPRs)
typedef __attribute__((ext_vector_type(4))) float f32x4;   // MFMA accumulator

__device__ __forceinline__ float bf2f(unsigned short u) {
    union { unsigned int i; float f; } v; v.i = ((unsigned int)u) << 16; return v.f;
}
__device__ __forceinline__ unsigned short f2bf(float f) {
    union { float f; unsigned int i; } v; v.f = f;
    unsigned int r = v.i + 0x7fffu + ((v.i >> 16) & 1u);
    return (unsigned short)(r >> 16);
}

// ---------------- zero the atomics region (ctr + pooled) ----------------
__global__ void k_zero(float4* __restrict__ p, int n16) {
    int i = blockIdx.x * blockDim.x + threadIdx.x;
    if (i < n16) p[i] = make_float4(0.f, 0.f, 0.f, 0.f);
}

// ---------------- fused: CSR scatter (E threads) + graph bounds (first N) ----------------
__global__ void k_setup(const int* __restrict__ src, const int* __restrict__ dst,
                        const int* __restrict__ batch,
                        int* __restrict__ counter, int* __restrict__ csr,
                        int* __restrict__ starts, int E, int N) {
    int e = blockIdx.x * blockDim.x + threadIdx.x;
    if (e < E) {
        int d = dst[e];
        int p = atomicAdd(&counter[d], 1);
        if (p < CAP) csr[d * CAP + p] = src[e];
    }
    if (e < N) {
        int b = batch[e];
        int prev = (e == 0) ? -1 : batch[e - 1];
        if (b != prev) {
            for (int g = prev + 1; g <= b; ++g) starts[g] = e;
        }
        if (e == N - 1) {
            for (int g = b + 1; g <= NGRAPH; ++g) starts[g] = N;
        }
    }
}

// ---------------- fused: dis = rsqrt(deg+1) ; x' = dis * x (bf16) ----------------
__global__ void k_disps(const float* __restrict__ x, const int* __restrict__ cnt,
                        float* __restrict__ dis, unsigned short* __restrict__ xp, int N) {
    int id = blockIdx.x * blockDim.x + threadIdx.x;
    if (id >= N * FEAT) return;
    int node = id >> 5;
    float dn = rsqrtf((float)(cnt[node] + 1));
    if ((id & 31) == 0) dis[node] = dn;
    xp[id] = f2bf(x[id] * dn);
}

// ---------------- both weights -> packed fragment-major bf16 ----------------
// Wp[((nb*(K/32) + ks)*64 + lane)*8 + j] = bf16(W[k][n]),
//   n = nb*16 + (lane&15), k = ks*32 + (lane>>4)*8 + j.
__device__ __forceinline__ void pack_w(const float* __restrict__ W,
                                       unsigned short* __restrict__ Wp, int K, int o) {
    int j    = o & 7;
    int lane = (o >> 3) & 63;
    int rest = o >> 9;
    int nst  = K >> 5;
    int ks   = rest & (nst - 1);
    int nb   = rest / nst;
    int n = nb * 16 + (lane & 15);
    int k = ks * 32 + (lane >> 4) * 8 + j;
    Wp[o] = f2bf(W[(size_t)k * HID + n]);
}
__global__ void k_cvtw(const float* __restrict__ W1, const float* __restrict__ W2,
                       unsigned short* __restrict__ W1p, unsigned short* __restrict__ W2p) {
    int o = blockIdx.x * blockDim.x + threadIdx.x;
    if (o < FEAT * HID) pack_w(W1, W1p, FEAT, o);
    int o2 = o - FEAT * HID;
    if (o2 >= 0 && o2 < HID * HID) pack_w(W2, W2p, HID, o2);
}

// ---------------- aggregate x' (32-wide bf16, pure gather-sum, x dn) ----------------
__global__ void k_aggx(const unsigned short* __restrict__ xp, const int* __restrict__ cnt,
                       const int* __restrict__ csr, const float* __restrict__ dis,
                       unsigned short* __restrict__ out, int N) {
    int node = blockIdx.x * 8 + (threadIdx.x >> 5);
    if (node >= N) return;
    int col = threadIdx.x & 31;
    float acc = bf2f(xp[(size_t)node * FEAT + col]);      // self term (pre-scaled)
    int e = cnt[node]; if (e > CAP) e = CAP;
    const int* lst = &csr[(size_t)node * CAP];
    int i = 0;
    for (; i + 4 <= e; i += 4) {
        int4 s4 = *(const int4*)&lst[i];
        float v0 = bf2f(xp[(size_t)s4.x * FEAT + col]);
        float v1 = bf2f(xp[(size_t)s4.y * FEAT + col]);
        float v2 = bf2f(xp[(size_t)s4.z * FEAT + col]);
        float v3 = bf2f(xp[(size_t)s4.w * FEAT + col]);
        acc += (v0 + v1) + (v2 + v3);
    }
    for (; i < e; ++i) acc += bf2f(xp[(size_t)lst[i] * FEAT + col]);
    out[(size_t)node * FEAT + col] = f2bf(acc * dis[node]);
}

// ---------------- aggregate h' (256-wide bf16, 8 gathers in flight, x dn) ----------------
__global__ void k_aggh(const unsigned short* __restrict__ h, const int* __restrict__ cnt,
                       const int* __restrict__ csr, const float* __restrict__ dis,
                       unsigned short* __restrict__ out, int N) {
    int wid = (int)((blockIdx.x * (size_t)blockDim.x + threadIdx.x) >> 6);
    if (wid >= N) return;
    int lane = threadIdx.x & 63;
    int c0 = lane * 4;

    ushort4 hv = *(const ushort4*)&h[(size_t)wid * HID + c0];   // self term (pre-scaled)
    float a0 = bf2f(hv.x), a1 = bf2f(hv.y), a2 = bf2f(hv.z), a3 = bf2f(hv.w);

    int e = cnt[wid]; if (e > CAP) e = CAP;
    const int* lst = &csr[(size_t)wid * CAP];
    int i = 0;
    for (; i + 8 <= e; i += 8) {
        int4 sa = *(const int4*)&lst[i];
        int4 sb = *(const int4*)&lst[i + 4];
        ushort4 v0 = *(const ushort4*)&h[(size_t)sa.x * HID + c0];
        ushort4 v1 = *(const ushort4*)&h[(size_t)sa.y * HID + c0];
        ushort4 v2 = *(const ushort4*)&h[(size_t)sa.z * HID + c0];
        ushort4 v3 = *(const ushort4*)&h[(size_t)sa.w * HID + c0];
        ushort4 v4 = *(const ushort4*)&h[(size_t)sb.x * HID + c0];
        ushort4 v5 = *(const ushort4*)&h[(size_t)sb.y * HID + c0];
        ushort4 v6 = *(const ushort4*)&h[(size_t)sb.z * HID + c0];
        ushort4 v7 = *(const ushort4*)&h[(size_t)sb.w * HID + c0];
        a0 += ((bf2f(v0.x) + bf2f(v1.x)) + (bf2f(v2.x) + bf2f(v3.x)))
            + ((bf2f(v4.x) + bf2f(v5.x)) + (bf2f(v6.x) + bf2f(v7.x)));
        a1 += ((bf2f(v0.y) + bf2f(v1.y)) + (bf2f(v2.y) + bf2f(v3.y)))
            + ((bf2f(v4.y) + bf2f(v5.y)) + (bf2f(v6.y) + bf2f(v7.y)));
        a2 += ((bf2f(v0.z) + bf2f(v1.z)) + (bf2f(v2.z) + bf2f(v3.z)))
            + ((bf2f(v4.z) + bf2f(v5.z)) + (bf2f(v6.z) + bf2f(v7.z)));
        a3 += ((bf2f(v0.w) + bf2f(v1.w)) + (bf2f(v2.w) + bf2f(v3.w)))
            + ((bf2f(v4.w) + bf2f(v5.w)) + (bf2f(v6.w) + bf2f(v7.w)));
    }
    for (; i + 4 <= e; i += 4) {
        int4 s4 = *(const int4*)&lst[i];
        ushort4 v0 = *(const ushort4*)&h[(size_t)s4.x * HID + c0];
        ushort4 v1 = *(const ushort4*)&h[(size_t)s4.y * HID + c0];
        ushort4 v2 = *(const ushort4*)&h[(size_t)s4.z * HID + c0];
        ushort4 v3 = *(const ushort4*)&h[(size_t)s4.w * HID + c0];
        a0 += (bf2f(v0.x) + bf2f(v1.x)) + (bf2f(v2.x) + bf2f(v3.x));
        a1 += (bf2f(v0.y) + bf2f(v1.y)) + (bf2f(v2.y) + bf2f(v3.y));
        a2 += (bf2f(v0.z) + bf2f(v1.z)) + (bf2f(v2.z) + bf2f(v3.z));
        a3 += (bf2f(v0.w) + bf2f(v1.w)) + (bf2f(v2.w) + bf2f(v3.w));
    }
    for (; i < e; ++i) {
        ushort4 v = *(const ushort4*)&h[(size_t)lst[i] * HID + c0];
        a0 += bf2f(v.x); a1 += bf2f(v.y); a2 += bf2f(v.z); a3 += bf2f(v.w);
    }
    float dn = dis[wid];
    ushort4 o;
    o.x = f2bf(a0 * dn); o.y = f2bf(a1 * dn); o.z = f2bf(a2 * dn); o.w = f2bf(a3 * dn);
    *(ushort4*)&out[(size_t)wid * HID + c0] = o;
}

// ---------------- bf16 MFMA GEMM: C = scale * relu(A[M,K] @ W + bias) ----------------
// 256 thr = 4 waves. Block tile 64(M) x 256(N, full HID); wave tile 64x64.
__global__ __launch_bounds__(256, 4)
void k_mmf(const unsigned short* __restrict__ A, const unsigned short* __restrict__ Wp,
           const float* __restrict__ bias, const float* __restrict__ scale,
           unsigned short* __restrict__ C, int M, int K, int lgK) {
    __shared__ unsigned short lds[64 * 264];
    int tid  = threadIdx.x;
    int lane = tid & 63;
    int wid  = tid >> 6;
    int l15  = lane & 15;
    int lq   = lane >> 4;
    int row0 = blockIdx.x * 64;

    const int P = K + 8;
    int iters = (64 * K) >> 11;
    for (int it = 0; it < iters; ++it) {
        int flat = (it * 256 + tid) * 8;
        int row = flat >> lgK;
        int col = flat & (K - 1);
        bfrag v = {0, 0, 0, 0, 0, 0, 0, 0};
        int gr = row0 + row;
        if (gr < M) v = *(const bfrag*)&A[(size_t)gr * K + col];
        *(bfrag*)&lds[row * P + col] = v;
    }
    __syncthreads();

    int nsteps = K >> 5;
    f32x4 acc[4][4];
#pragma unroll
    for (int mi = 0; mi < 4; ++mi)
#pragma unroll
        for (int ni = 0; ni < 4; ++ni) acc[mi][ni] = (f32x4){0.f, 0.f, 0.f, 0.f};

    for (int ks = 0; ks < nsteps; ++ks) {
        bfrag fb[4];
#pragma unroll
        for (int ni = 0; ni < 4; ++ni) {
            size_t off = (((size_t)(wid * 4 + ni) * nsteps + ks) * 64 + lane) * 8;
            fb[ni] = *(const bfrag*)&Wp[off];
        }
        bfrag fa[4];
        int koff = ks * 32 + lq * 8;
#pragma unroll
        for (int mi = 0; mi < 4; ++mi)
            fa[mi] = *(const bfrag*)&lds[(mi * 16 + l15) * P + koff];
#pragma unroll
        for (int mi = 0; mi < 4; ++mi)
#pragma unroll
            for (int ni = 0; ni < 4; ++ni)
                acc[mi][ni] = __builtin_amdgcn_mfma_f32_16x16x32_bf16(fb[ni], fa[mi], acc[mi][ni], 0, 0, 0);
    }

    float4 bv[4];
#pragma unroll
    for (int ni = 0; ni < 4; ++ni)
        bv[ni] = *(const float4*)&bias[(wid * 4 + ni) * 16 + lq * 4];
    float sv[4];
#pragma unroll
    for (int mi = 0; mi < 4; ++mi) {
        int gr = row0 + mi * 16 + l15;
        sv[mi] = (gr < M) ? scale[gr] : 0.f;
    }

    __syncthreads();
#pragma unroll
    for (int mi = 0; mi < 4; ++mi) {
#pragma unroll
        for (int ni = 0; ni < 4; ++ni) {
            const float* bp = (const float*)&bv[ni];
            ushort4 o;
            o.x = f2bf(fmaxf(acc[mi][ni][0] + bp[0], 0.f) * sv[mi]);
            o.y = f2bf(fmaxf(acc[mi][ni][1] + bp[1], 0.f) * sv[mi]);
            o.z = f2bf(fmaxf(acc[mi][ni][2] + bp[2], 0.f) * sv[mi]);
            o.w = f2bf(fmaxf(acc[mi][ni][3] + bp[3], 0.f) * sv[mi]);
            *(ushort4*)&lds[(mi * 16 + l15) * 264 + (wid * 4 + ni) * 16 + lq * 4] = o;
        }
    }
    __syncthreads();

#pragma unroll
    for (int i = 0; i < 8; ++i) {
        int F = (i * 256 + tid) * 8;
        int row = F >> 8;
        int col = F & 255;
        int gr = row0 + row;
        if (gr < M) {
            bfrag v = *(const bfrag*)&lds[row * 264 + col];
            *(bfrag*)&C[(size_t)gr * HID + col] = v;
        }
    }
}

// ---------------- layer-2 GEMM fused with mean-pool (no h2 buffer) ----------------
// Same compute as k_mmf (K=256, no scale); epilogue segment-reduces the 64-row
// LDS tile per column and atomically adds at graph boundaries.
__global__ __launch_bounds__(256, 4)
void k_mmfp(const unsigned short* __restrict__ A, const unsigned short* __restrict__ Wp,
            const float* __restrict__ bias, const int* __restrict__ batch,
            float* __restrict__ pooled, int M) {
    __shared__ unsigned short lds[64 * 264];
    __shared__ int bshare[64];
    const int K = HID;
    int tid  = threadIdx.x;
    int lane = tid & 63;
    int wid  = tid >> 6;
    int l15  = lane & 15;
    int lq   = lane >> 4;
    int row0 = blockIdx.x * 64;

    if (tid < 64) {
        int gr = row0 + tid;
        bshare[tid] = (gr < M) ? batch[gr] : -1;
    }

    const int P = K + 8;
    for (int it = 0; it < 8; ++it) {
        int flat = (it * 256 + tid) * 8;
        int row = flat >> 8;
        int col = flat & 255;
        bfrag v = {0, 0, 0, 0, 0, 0, 0, 0};
        int gr = row0 + row;
        if (gr < M) v = *(const bfrag*)&A[(size_t)gr * K + col];
        *(bfrag*)&lds[row * P + col] = v;
    }
    __syncthreads();

    f32x4 acc[4][4];
#pragma unroll
    for (int mi = 0; mi < 4; ++mi)
#pragma unroll
        for (int ni = 0; ni < 4; ++ni) acc[mi][ni] = (f32x4){0.f, 0.f, 0.f, 0.f};

    for (int ks = 0; ks < 8; ++ks) {
        bfrag fb[4];
#pragma unroll
        for (int ni = 0; ni < 4; ++ni) {
            size_t off = (((size_t)(wid * 4 + ni) * 8 + ks) * 64 + lane) * 8;
            fb[ni] = *(const bfrag*)&Wp[off];
        }
        bfrag fa[4];
        int koff = ks * 32 + lq * 8;
#pragma unroll
        for (int mi = 0; mi < 4; ++mi)
            fa[mi] = *(const bfrag*)&lds[(mi * 16 + l15) * P + koff];
#pragma unroll
        for (int mi = 0; mi < 4; ++mi)
#pragma unroll
            for (int ni = 0; ni < 4; ++ni)
                acc[mi][ni] = __builtin_amdgcn_mfma_f32_16x16x32_bf16(fb[ni], fa[mi], acc[mi][ni], 0, 0, 0);
    }

    float4 bv[4];
#pragma unroll
    for (int ni = 0; ni < 4; ++ni)
        bv[ni] = *(const float4*)&bias[(wid * 4 + ni) * 16 + lq * 4];

    __syncthreads();
#pragma unroll
    for (int mi = 0; mi < 4; ++mi) {
#pragma unroll
        for (int ni = 0; ni < 4; ++ni) {
            const float* bp = (const float*)&bv[ni];
            ushort4 o;
            o.x = f2bf(fmaxf(acc[mi][ni][0] + bp[0], 0.f));
            o.y = f2bf(fmaxf(acc[mi][ni][1] + bp[1], 0.f));
            o.z = f2bf(fmaxf(acc[mi][ni][2] + bp[2], 0.f));
            o.w = f2bf(fmaxf(acc[mi][ni][3] + bp[3], 0.f));
            *(ushort4*)&lds[(mi * 16 + l15) * 264 + (wid * 4 + ni) * 16 + lq * 4] = o;
        }
    }
    __syncthreads();

    // segment-reduce 64 rows for column c = tid; flush at graph boundary
    int c = tid;
    float pacc = 0.f;
    int cur = bshare[0];
    for (int r = 0; r < 64; ++r) {
        int g = bshare[r];
        if (g != cur) {
            if (cur >= 0) atomicAdd(&pooled[(size_t)cur * HID + c], pacc);
            pacc = 0.f; cur = g;
        }
        pacc += bf2f(lds[r * 264 + c]);
    }
    if (cur >= 0) atomicAdd(&pooled[(size_t)cur * HID + c], pacc);
}

// ---------------- head ----------------
__global__ void k_head(const float* __restrict__ pooled, const int* __restrict__ starts,
                       const float* __restrict__ Wf, const float* __restrict__ bf,
                       float* __restrict__ out) {
    int t = blockIdx.x * blockDim.x + threadIdx.x;
    if (t >= NGRAPH * 12) return;
    int g = t / 12, j = t % 12;
    float cntf = (float)(starts[g + 1] - starts[g]);
    float inv = 1.f / fmaxf(cntf, 1.f);
    float s = 0.f;
    for (int k = 0; k < HID; ++k) s += pooled[(size_t)g * HID + k] * Wf[k * 12 + j];
    s = s * inv + bf[j];
    if (j < 6) {
        out[g * 6 + j] = s;
    } else {
        float ls = fminf(fmaxf(s, -20.f), 2.f);
        out[NGRAPH * 6 + g * 6 + (j - 6)] = expf(ls);
    }
}

// ---------------- launch ----------------
extern "C" void kernel_launch(void* const* d_in, const int* in_sizes, int n_in,
                              void* d_out, int out_size, void* d_ws, size_t ws_size,
                              hipStream_t stream) {
    const float* x     = (const float*)d_in[0];
    const int*   ei    = (const int*)d_in[1];
    const int*   batch = (const int*)d_in[2];
    const float* W1    = (const float*)d_in[3];
    const float* b1    = (const float*)d_in[4];
    const float* W2    = (const float*)d_in[5];
    const float* b2    = (const float*)d_in[6];
    const float* Wf    = (const float*)d_in[7];
    const float* bfv   = (const float*)d_in[8];
    float* out = (float*)d_out;

    const int E = in_sizes[1] / 2;
    const int N = in_sizes[2];
    const int* srcp = ei;
    const int* dstp = ei + E;

    // workspace layout
    char* ws = (char*)d_ws;
    const size_t OFF_CTR    = 0;            // int[NN]            -> 200192
    const size_t OFF_POOLED = 200192;       // f32[64*256]        -> 265728
    const size_t ZERO_BYTES = 265728;
    const size_t OFF_STARTS = 265728;       // int[65]            -> 266240
    const size_t OFF_DIS    = 266240;       // f32[NN]            -> 466432
    const size_t OFF_W1P    = 466432;       // bf16[32*256]       -> 482816
    const size_t OFF_W2P    = 482816;       // bf16[256*256]      -> 613888
    const size_t OFF_CSR    = 613888;       // int[NN*CAP]        -> 13413888
    const size_t OFF_XP     = 13413888;     // bf16[NN*32]        -> 16613888
    const size_t OFF_AGGX   = 16613888;     // bf16[NN*32]        -> 19813888
    const size_t OFF_H1     = 19813888;     // bf16[NN*256]       -> 45413888
    const size_t OFF_G      = 45413888;     // bf16[NN*256]       -> 71013888

    int*            ctr    = (int*)(ws + OFF_CTR);
    float*          pooled = (float*)(ws + OFF_POOLED);
    int*            starts = (int*)(ws + OFF_STARTS);
    float*          dis    = (float*)(ws + OFF_DIS);
    unsigned short* W1p    = (unsigned short*)(ws + OFF_W1P);
    unsigned short* W2p    = (unsigned short*)(ws + OFF_W2P);
    int*            csr    = (int*)(ws + OFF_CSR);
    unsigned short* xp     = (unsigned short*)(ws + OFF_XP);
    unsigned short* aggX   = (unsigned short*)(ws + OFF_AGGX);
    unsigned short* h1     = (unsigned short*)(ws + OFF_H1);
    unsigned short* g      = (unsigned short*)(ws + OFF_G);

    const int T = 256;
    k_zero<<<(265728 / 16 + T - 1) / T, T, 0, stream>>>((float4*)ws, 265728 / 16);
    k_setup<<<(E + T - 1) / T, T, 0, stream>>>(srcp, dstp, batch, ctr, csr, starts, E, N);
    k_disps<<<(N * FEAT + T - 1) / T, T, 0, stream>>>(x, ctr, dis, xp, N);
    k_cvtw<<<((FEAT + HID) * HID + T - 1) / T, T, 0, stream>>>(W1, W2, W1p, W2p);

    // layer 1: aggX = dn*(sum x'[s] + x'[d]) ; h1 = dis * relu(aggX @ W1 + b1)
    k_aggx<<<(N + 7) / 8, T, 0, stream>>>(xp, ctr, csr, dis, aggX, N);
    k_mmf<<<(N + 63) / 64, T, 0, stream>>>(aggX, W1p, b1, dis, h1, N, FEAT, 5);

    // layer 2: g = dn*(sum h1'[s] + h1'[d]) ; pooled += segreduce(relu(g @ W2 + b2))
    k_aggh<<<(N * 64 + T - 1) / T, T, 0, stream>>>(h1, ctr, csr, dis, g, N);
    k_mmfp<<<(N + 63) / 64, T, 0, stream>>>(g, W2p, b2, batch, pooled, N);

    // head
    k_head<<<3, T, 0, stream>>>(pooled, starts, Wf, bfv, out);
}